// Round 13
// baseline (979.082 us; speedup 1.0000x reference)
//
#include <hip/hip_runtime.h>
#include <math.h>

#define N_PIX 4096  // H*W = 64*64
#define BATCH 4
#define LOG2E 1.4426950408889634f

typedef __bf16 bf16x8 __attribute__((ext_vector_type(8)));
typedef __bf16 bf16x4v __attribute__((ext_vector_type(4)));
typedef float f32x4 __attribute__((ext_vector_type(4)));

// ---------------------------------------------------------------------------
// Fused spectral norms: one block per layer, 1024 threads (16 waves).
// ---------------------------------------------------------------------------
struct SigP {
    const float* W[5];
    const float* u[5];
    int O[5];
    int C[5];
};

__global__ __launch_bounds__(1024)
void sigma_all(SigP p, float* __restrict__ out_inv) {
    __shared__ float ush[512];
    __shared__ float vsh[512];
    __shared__ float vpart[16 * 512];
    __shared__ float redl[1024];
    int L = blockIdx.x;
    const float* W = p.W[L];
    const float* u = p.u[L];
    int O = p.O[L], C = p.C[L];
    int t = threadIdx.x;
    int w = t >> 6, lane = t & 63;

    for (int i = t; i < O; i += 1024) ush[i] = u[i];
    __syncthreads();

    int o_beg = (O * w) >> 4, o_end = (O * (w + 1)) >> 4;
    for (int c = lane; c < C; c += 64) {
        float a = 0.f;
        for (int o = o_beg; o < o_end; ++o) a += W[(size_t)o * C + c] * ush[o];
        vpart[w * 512 + c] = a;
    }
    __syncthreads();

    float nn = 0.f;
    for (int c = t; c < C; c += 1024) {
        float s = 0.f;
        #pragma unroll
        for (int w2 = 0; w2 < 16; ++w2) s += vpart[w2 * 512 + c];
        vsh[c] = s;
        nn += s * s;
    }
    redl[t] = nn;
    __syncthreads();
    for (int s = 512; s > 0; s >>= 1) {
        if (t < s) redl[t] += redl[t + s];
        __syncthreads();
    }
    float nrm2 = redl[0];
    __syncthreads();
    float rinv = 1.f / (sqrtf(nrm2) + 1e-12f);

    float sq = 0.f;
    for (int o = w; o < O; o += 16) {
        float a = 0.f;
        for (int c = lane; c < C; c += 64) a += W[(size_t)o * C + c] * vsh[c];
        #pragma unroll
        for (int off = 1; off < 64; off <<= 1) a += __shfl_xor(a, off);
        if (lane == 0) sq += a * a;
    }
    if (lane == 0) redl[w] = sq;
    __syncthreads();
    if (t == 0) {
        float ns2raw = 0.f;
        #pragma unroll
        for (int i = 0; i < 16; ++i) ns2raw += redl[i];
        float ns2 = rinv * rinv * ns2raw;
        float sg = ns2 / (sqrtf(ns2) + 1e-12f);
        out_inv[L] = 1.f / sg;
    }
}

// ---------------------------------------------------------------------------
// Weight split: (O,C) fp32 * iv * scale -> (O, 2C) bf16  [hi | lo].
// ---------------------------------------------------------------------------
__global__ __launch_bounds__(256)
void wsplit_kernel(const float* __restrict__ W, const float* __restrict__ iv,
                   float scale, int C, __bf16* __restrict__ out) {
    int o = blockIdx.x;
    float s = (iv ? iv[0] : 1.f) * scale;
    for (int c = threadIdx.x; c < C; c += 256) {
        float wv = W[(size_t)o * C + c] * s;
        __bf16 hi = (__bf16)wv;
        float lo = wv - (float)hi;
        out[(size_t)o * 2 * C + c] = hi;
        out[(size_t)o * 2 * C + C + c] = (__bf16)lo;
    }
}

// ---------------------------------------------------------------------------
// L1 only: fp32 VALU conv (C=6). x (B,C,N) -> out (B,O,N) fp32.
// ---------------------------------------------------------------------------
__global__ __launch_bounds__(256)
void conv_f32_kernel(const float* __restrict__ x, const float* __restrict__ W,
                     const float* __restrict__ bias, const float* __restrict__ sig,
                     float* __restrict__ out, int C, int O, int lrelu) {
    __shared__ float Ws[16][68];
    __shared__ float Xs[16][68];
    int t = threadIdx.x;
    int tx = t & 15, ty = t >> 4;
    int b = blockIdx.z;
    int n0 = blockIdx.x * 64, o0 = blockIdx.y * 64;
    float acc[4][4] = {};
    const float* xb = x + (size_t)b * C * N_PIX;
    for (int c0 = 0; c0 < C; c0 += 16) {
        #pragma unroll
        for (int i = 0; i < 4; ++i) {
            int e = t + i * 256;
            int o = e >> 4, c = e & 15;
            float wv = 0.f;
            if (o0 + o < O && c0 + c < C) wv = W[(size_t)(o0 + o) * C + c0 + c];
            Ws[c][o] = wv;
        }
        #pragma unroll
        for (int i = 0; i < 4; ++i) {
            int e = t + i * 256;
            int c = e >> 6, n = e & 63;
            float xv = 0.f;
            if (c0 + c < C) xv = xb[(size_t)(c0 + c) * N_PIX + n0 + n];
            Xs[c][n] = xv;
        }
        __syncthreads();
        #pragma unroll
        for (int cc = 0; cc < 16; ++cc) {
            float4 wv = *(const float4*)&Ws[cc][ty * 4];
            float4 xv = *(const float4*)&Xs[cc][tx * 4];
            float wa[4] = {wv.x, wv.y, wv.z, wv.w};
            float xa[4] = {xv.x, xv.y, xv.z, xv.w};
            #pragma unroll
            for (int i = 0; i < 4; ++i)
                #pragma unroll
                for (int j = 0; j < 4; ++j)
                    acc[i][j] += wa[i] * xa[j];
        }
        __syncthreads();
    }
    float ivv = sig ? sig[0] : 1.f;
    for (int i = 0; i < 4; ++i) {
        int o = o0 + ty * 4 + i;
        if (o >= O) break;
        float bv = bias[o];
        float vres[4];
        #pragma unroll
        for (int j = 0; j < 4; ++j) {
            float v = acc[i][j] * ivv + bv;
            if (lrelu) v = (v > 0.f) ? v : 0.1f * v;
            vres[j] = v;
        }
        *(float4*)&out[((size_t)b * O + o) * N_PIX + n0 + tx * 4] =
            make_float4(vres[0], vres[1], vres[2], vres[3]);
    }
}

// ---------------------------------------------------------------------------
// Transpose+split: (B,64,N) fp32 -> (B,N,128) bf16 [hi(64)|lo(64)].
// ---------------------------------------------------------------------------
__global__ __launch_bounds__(256)
void tsplit64_kernel(const float* __restrict__ in, __bf16* __restrict__ out) {
    __shared__ float tile[64 * 65];
    int t = threadIdx.x;
    int n0 = blockIdx.x * 64, b = blockIdx.y;
    for (int e = t; e < 64 * 64; e += 256) {
        int c = e >> 6, n = e & 63;
        tile[n * 65 + c] = in[((size_t)b * 64 + c) * N_PIX + n0 + n];
    }
    __syncthreads();
    for (int e = t; e < 64 * 64; e += 256) {
        int n = e >> 6, c = e & 63;
        float v = tile[n * 65 + c];
        __bf16 hi = (__bf16)v;
        size_t base = ((size_t)b * N_PIX + n0 + n) * 128;
        out[base + c] = hi;
        out[base + 64 + c] = (__bf16)(v - (float)hi);
    }
}

// ---------------------------------------------------------------------------
// Split-bf16 MFMA 1x1 conv (unchanged).
// ---------------------------------------------------------------------------
template <int WO, int WN, int MODE, int IN_F32, int LRELU>
__global__ __launch_bounds__(256)
void mfma_conv(const void* __restrict__ xt, const __bf16* __restrict__ wsp,
               const float* __restrict__ bias, float bscale,
               void* __restrict__ outp, int C, int O) {
    constexpr int NT_BLK = WN * 128;
    __shared__ __bf16 Ws[WO * 32 * 72];
    __shared__ __bf16 Xs[NT_BLK * 72];
    int t = threadIdx.x;
    int lane = t & 63, w = t >> 6;
    int l15 = lane & 15, quad = lane >> 4;
    int wo = w / WN, wn = w % WN;
    int b = blockIdx.z;
    int n0b = blockIdx.x * NT_BLK, o0b = blockIdx.y * WO * 32;

    f32x4 acc[2][8] = {};

    for (int c0 = 0; c0 < C; c0 += 32) {
        __syncthreads();
        for (int e = t; e < WO * 32 * 8; e += 256) {
            int row = e >> 3, part = e & 7;
            size_t src = (size_t)(o0b + row) * 2 * C +
                         (part < 4 ? c0 + part * 8 : C + c0 + (part - 4) * 8);
            int dst = row * 72 + (part < 4 ? part * 8 : 32 + (part - 4) * 8);
            *(uint4*)&Ws[dst] = *(const uint4*)&wsp[src];
        }
        if (IN_F32) {
            const float* xf = (const float*)xt;
            for (int e = t; e < NT_BLK * 8; e += 256) {
                int row = e >> 3, part = e & 7;
                float4 v = *(const float4*)&xf[((size_t)b * N_PIX + n0b + row) * C + c0 + part * 4];
                bf16x4v hi, lo;
                float va[4] = {v.x, v.y, v.z, v.w};
                #pragma unroll
                for (int j = 0; j < 4; ++j) {
                    hi[j] = (__bf16)va[j];
                    lo[j] = (__bf16)(va[j] - (float)hi[j]);
                }
                *(bf16x4v*)&Xs[row * 72 + part * 4] = hi;
                *(bf16x4v*)&Xs[row * 72 + 32 + part * 4] = lo;
            }
        } else {
            const __bf16* xb = (const __bf16*)xt;
            for (int e = t; e < NT_BLK * 8; e += 256) {
                int row = e >> 3, part = e & 7;
                size_t src = ((size_t)b * N_PIX + n0b + row) * 2 * C +
                             (part < 4 ? c0 + part * 8 : C + c0 + (part - 4) * 8);
                int dst = row * 72 + (part < 4 ? part * 8 : 32 + (part - 4) * 8);
                *(uint4*)&Xs[dst] = *(const uint4*)&xb[src];
            }
        }
        __syncthreads();

        bf16x8 ah[2], al[2];
        #pragma unroll
        for (int mf = 0; mf < 2; ++mf) {
            int base = (wo * 32 + mf * 16 + l15) * 72 + quad * 8;
            ah[mf] = *(const bf16x8*)&Ws[base];
            al[mf] = *(const bf16x8*)&Ws[base + 32];
        }
        #pragma unroll
        for (int nt = 0; nt < 8; ++nt) {
            int bbase = (wn * 128 + nt * 16 + l15) * 72 + quad * 8;
            bf16x8 bh = *(const bf16x8*)&Xs[bbase];
            bf16x8 bl = *(const bf16x8*)&Xs[bbase + 32];
            #pragma unroll
            for (int mf = 0; mf < 2; ++mf) {
                acc[mf][nt] = __builtin_amdgcn_mfma_f32_16x16x32_bf16(ah[mf], bh, acc[mf][nt], 0, 0, 0);
                acc[mf][nt] = __builtin_amdgcn_mfma_f32_16x16x32_bf16(ah[mf], bl, acc[mf][nt], 0, 0, 0);
                acc[mf][nt] = __builtin_amdgcn_mfma_f32_16x16x32_bf16(al[mf], bh, acc[mf][nt], 0, 0, 0);
            }
        }
    }

    float bv[2][4];
    #pragma unroll
    for (int mf = 0; mf < 2; ++mf)
        #pragma unroll
        for (int r = 0; r < 4; ++r)
            bv[mf][r] = bias[o0b + wo * 32 + mf * 16 + quad * 4 + r] * bscale;

    #pragma unroll
    for (int mf = 0; mf < 2; ++mf)
        #pragma unroll
        for (int nt = 0; nt < 8; ++nt) {
            int n = n0b + wn * 128 + nt * 16 + l15;
            float val[4];
            #pragma unroll
            for (int r = 0; r < 4; ++r) {
                float v = acc[mf][nt][r] + bv[mf][r];
                if (LRELU) v = (v > 0.f) ? v : 0.1f * v;
                val[r] = v;
            }
            int obase = o0b + wo * 32 + mf * 16 + quad * 4;
            if (MODE == 1) {
                __bf16* ob = (__bf16*)outp;
                #pragma unroll
                for (int r = 0; r < 4; ++r)
                    ob[((size_t)b * O + obase + r) * N_PIX + n] = (__bf16)val[r];
            } else if (MODE == 2) {
                __bf16* ob = (__bf16*)outp;
                bf16x4v hv, lv;
                #pragma unroll
                for (int r = 0; r < 4; ++r) {
                    hv[r] = (__bf16)val[r];
                    lv[r] = (__bf16)(val[r] - (float)hv[r]);
                }
                size_t rb = ((size_t)b * N_PIX + n) * 2 * O + obase;
                *(bf16x4v*)&ob[rb] = hv;
                *(bf16x4v*)&ob[rb + O] = lv;
            } else {  // MODE 4
                __bf16* ob = (__bf16*)outp;
                bf16x4v hv;
                #pragma unroll
                for (int r = 0; r < 4; ++r) hv[r] = (__bf16)val[r];
                *(bf16x4v*)&ob[((size_t)b * N_PIX + n) * O + obase] = hv;
            }
        }
}

// ---------------------------------------------------------------------------
// Attention kernel 1/3: S[b,q,k] raw scores (exp2-domain), bf16.
// ---------------------------------------------------------------------------
template <int CQ>
__global__ __launch_bounds__(256)
void s_gemm(const __bf16* __restrict__ qt, const __bf16* __restrict__ kt,
            __bf16* __restrict__ S) {
    constexpr int NKK = CQ / 32;
    __shared__ __bf16 Ss[128 * 136];
    int t = threadIdx.x;
    int lane = t & 63, w = t >> 6;
    int l15 = lane & 15, quad = lane >> 4;
    int k0 = blockIdx.x * 128, q0 = blockIdx.y * 128, b = blockIdx.z;

    bf16x8 kf[2][NKK], qf[8][NKK];
    #pragma unroll
    for (int mf = 0; mf < 2; ++mf)
        #pragma unroll
        for (int kk = 0; kk < NKK; ++kk)
            kf[mf][kk] = *(const bf16x8*)&kt[((size_t)b * N_PIX + k0 + w * 32 + mf * 16 + l15) * CQ + kk * 32 + quad * 8];
    #pragma unroll
    for (int nt = 0; nt < 8; ++nt)
        #pragma unroll
        for (int kk = 0; kk < NKK; ++kk)
            qf[nt][kk] = *(const bf16x8*)&qt[((size_t)b * N_PIX + q0 + nt * 16 + l15) * CQ + kk * 32 + quad * 8];

    f32x4 acc[2][8] = {};
    #pragma unroll
    for (int kk = 0; kk < NKK; ++kk)
        #pragma unroll
        for (int mf = 0; mf < 2; ++mf)
            #pragma unroll
            for (int nt = 0; nt < 8; ++nt)
                acc[mf][nt] = __builtin_amdgcn_mfma_f32_16x16x32_bf16(kf[mf][kk], qf[nt][kk], acc[mf][nt], 0, 0, 0);

    #pragma unroll
    for (int mf = 0; mf < 2; ++mf)
        #pragma unroll
        for (int nt = 0; nt < 8; ++nt) {
            bf16x4v pk;
            #pragma unroll
            for (int r = 0; r < 4; ++r) pk[r] = (__bf16)acc[mf][nt][r];
            *(bf16x4v*)&Ss[(nt * 16 + l15) * 136 + w * 32 + mf * 16 + quad * 4] = pk;
        }
    __syncthreads();
    int ql = t >> 1, kh = (t & 1) * 64;
    size_t row = ((size_t)b * N_PIX + q0 + ql) * N_PIX + k0 + kh;
    #pragma unroll
    for (int j = 0; j < 8; ++j)
        *(uint4*)&S[row + j * 8] = *(const uint4*)&Ss[ql * 136 + kh + j * 8];
}

// ---------------------------------------------------------------------------
// Attention kernel 2/3: in-place row softmax on S (exp2 domain), applied ONCE.
// One wave per 4096-key row; 4 rows/block.
// ---------------------------------------------------------------------------
__global__ __launch_bounds__(256)
void softmax_rows(__bf16* __restrict__ S) {
    int t = threadIdx.x;
    int lane = t & 63, w = t >> 6;
    __bf16* Sr = S + ((size_t)blockIdx.x * 4 + w) * N_PIX;
    bf16x8 v[8];
    #pragma unroll
    for (int j = 0; j < 8; ++j) v[j] = *(const bf16x8*)&Sr[j * 512 + lane * 8];
    float m = -1e30f;
    #pragma unroll
    for (int j = 0; j < 8; ++j)
        #pragma unroll
        for (int e = 0; e < 8; ++e) m = fmaxf(m, (float)v[j][e]);
    #pragma unroll
    for (int off = 1; off < 64; off <<= 1) m = fmaxf(m, __shfl_xor(m, off));
    float s = 0.f;
    #pragma unroll
    for (int j = 0; j < 8; ++j)
        #pragma unroll
        for (int e = 0; e < 8; ++e) {
            float p = exp2f((float)v[j][e] - m);
            s += p;
            v[j][e] = (__bf16)p;
        }
    #pragma unroll
    for (int off = 1; off < 64; off <<= 1) s += __shfl_xor(s, off);
    float il = 1.f / s;
    #pragma unroll
    for (int j = 0; j < 8; ++j) {
        #pragma unroll
        for (int e = 0; e < 8; ++e) v[j][e] = (__bf16)((float)v[j][e] * il);
        *(bf16x8*)&Sr[j * 512 + lane * 8] = v[j];
    }
}

// ---------------------------------------------------------------------------
// Attention kernel 3/3: LDS-staged PV GEMM, M=64 q-tile, grid 2048 (8 blk/CU).
// O[b,q,c] = gamma * sum_k P[b,q,k] V[b,c,k] + residual.
// Block: 64 q x NT*16 c, 4 waves (16 q/wave).  Grid 2048 = 8 cblk x 256 pair;
// bid%8 == pair%8 pins all c-block sharers of one (q0,b) P-slab to one XCD.
// LDS: Psh 9.2KB + Vsh (NT=4: 9.2KB / NT=2: 4.6KB) -> 8 blocks/CU fit.
// ---------------------------------------------------------------------------
template <int NT>
__global__ __launch_bounds__(256)
void pv_gemm4(const __bf16* __restrict__ P, const __bf16* __restrict__ vg,
              const __bf16* __restrict__ xin2, const float* __restrict__ gamma,
              float* __restrict__ out, int C) {
    constexpr int CCH = NT * 16;
    __shared__ __bf16 Psh[64 * 72];
    __shared__ __bf16 Vsh[CCH * 72];
    int t = threadIdx.x;
    int lane = t & 63, w = t >> 6;
    int l15 = lane & 15, quad = lane >> 4;
    int bid = blockIdx.x;
    int pair = bid & 255, cblk = bid >> 8;
    int qi = pair >> 2, b = pair & 3;
    int q0 = qi * 64, c0 = cblk * CCH;
    const __bf16* Pb = P + ((size_t)b * N_PIX + q0) * N_PIX;
    const __bf16* Vb = vg + ((size_t)b * C + c0) * N_PIX;

    f32x4 acc[NT] = {};

    for (int k0 = 0; k0 < N_PIX; k0 += 64) {
        __syncthreads();
        #pragma unroll
        for (int i = 0; i < 2; ++i) {  // P tile: 64 q-rows x 64 k
            int e = t + i * 256;
            int row = e >> 3, seg = e & 7;
            *(uint4*)&Psh[row * 72 + seg * 8] = *(const uint4*)&Pb[(size_t)row * N_PIX + k0 + seg * 8];
        }
        #pragma unroll
        for (int i = 0; i < CCH / 32; ++i) {  // V tile: CCH c-rows x 64 k
            int e = t + i * 256;
            int row = e >> 3, seg = e & 7;
            *(uint4*)&Vsh[row * 72 + seg * 8] = *(const uint4*)&Vb[(size_t)row * N_PIX + k0 + seg * 8];
        }
        __syncthreads();
        #pragma unroll
        for (int kk = 0; kk < 2; ++kk) {
            bf16x8 pa = *(const bf16x8*)&Psh[(w * 16 + l15) * 72 + kk * 32 + quad * 8];
            #pragma unroll
            for (int nt = 0; nt < NT; ++nt) {
                bf16x8 vf = *(const bf16x8*)&Vsh[(nt * 16 + l15) * 72 + kk * 32 + quad * 8];
                acc[nt] = __builtin_amdgcn_mfma_f32_16x16x32_bf16(pa, vf, acc[nt], 0, 0, 0);
            }
        }
    }

    float g = gamma[0];
    #pragma unroll
    for (int r = 0; r < 4; ++r) {
        int q = q0 + w * 16 + quad * 4 + r;
        size_t xrb = ((size_t)b * N_PIX + q) * 2 * C;
        size_t orb = ((size_t)b * N_PIX + q) * C;
        #pragma unroll
        for (int nt = 0; nt < NT; ++nt) {
            int c = c0 + nt * 16 + l15;
            float xr = (float)xin2[xrb + c] + (float)xin2[xrb + C + c];
            out[orb + c] = g * acc[nt][r] + xr;
        }
    }
}

// ---------------------------------------------------------------------------
// L5: out[b,n] = lrelu(iv * dot(W5, h[b,n,:]) + b5).  h: (B,N,512) fp32.
// ---------------------------------------------------------------------------
__global__ __launch_bounds__(256)
void l5_kernel(const float* __restrict__ h, const float* __restrict__ W5,
               const float* __restrict__ b5, const float* __restrict__ sig,
               float* __restrict__ out) {
    int t = threadIdx.x;
    int lane = t & 63, w = t >> 6;
    int p = blockIdx.x * 4 + w;
    const float* row = h + (size_t)p * 512;
    float4 a0 = *(const float4*)&row[lane * 8];
    float4 a1 = *(const float4*)&row[lane * 8 + 4];
    float4 w0 = *(const float4*)&W5[lane * 8];
    float4 w1 = *(const float4*)&W5[lane * 8 + 4];
    float s = a0.x * w0.x + a0.y * w0.y + a0.z * w0.z + a0.w * w0.w +
              a1.x * w1.x + a1.y * w1.y + a1.z * w1.z + a1.w * w1.w;
    #pragma unroll
    for (int off = 1; off < 64; off <<= 1) s += __shfl_xor(s, off);
    if (lane == 0) {
        float v = sig[0] * s + b5[0];
        out[p] = (v > 0.f) ? v : 0.1f * v;
    }
}

// ---------------------------------------------------------------------------
// Launcher
// ---------------------------------------------------------------------------
extern "C" void kernel_launch(void* const* d_in, const int* in_sizes, int n_in,
                              void* d_out, int out_size, void* d_ws, size_t ws_size,
                              hipStream_t stream) {
    const float* x   = (const float*)d_in[0];
    const float* W1  = (const float*)d_in[1];
    const float* b1  = (const float*)d_in[2];
    const float* u1  = (const float*)d_in[3];
    const float* W2  = (const float*)d_in[4];
    const float* b2  = (const float*)d_in[5];
    const float* u2  = (const float*)d_in[6];
    const float* W3  = (const float*)d_in[7];
    const float* b3  = (const float*)d_in[8];
    const float* u3  = (const float*)d_in[9];
    const float* W4  = (const float*)d_in[10];
    const float* b4  = (const float*)d_in[11];
    const float* u4  = (const float*)d_in[12];
    const float* W5  = (const float*)d_in[13];
    const float* b5  = (const float*)d_in[14];
    const float* u5  = (const float*)d_in[15];
    const float* a1_qW = (const float*)d_in[16];
    const float* a1_qb = (const float*)d_in[17];
    const float* a1_kW = (const float*)d_in[18];
    const float* a1_kb = (const float*)d_in[19];
    const float* a1_vW = (const float*)d_in[20];
    const float* a1_vb = (const float*)d_in[21];
    const float* a1_g  = (const float*)d_in[22];
    const float* a2_qW = (const float*)d_in[23];
    const float* a2_qb = (const float*)d_in[24];
    const float* a2_kW = (const float*)d_in[25];
    const float* a2_kb = (const float*)d_in[26];
    const float* a2_vW = (const float*)d_in[27];
    const float* a2_vb = (const float*)d_in[28];
    const float* a2_g  = (const float*)d_in[29];

    float* ws = (float*)d_ws;
    const size_t NF = (size_t)BATCH * N_PIX;  // 16384
    float* sig    = ws;                       // 16
    float* h1     = ws + 16;                  // NF*64 fl
    float* slabC  = h1 + NF * 64;             // NF*512 fl
    float* slabS1 = slabC + NF * 512;         // NF*256 fl
    float* slabS2 = slabS1 + NF * 256;        // NF*512 fl
    float* qtf    = slabS2 + NF * 512;        // NF*32 fl
    float* ktf    = qtf + NF * 32;            // NF*32 fl
    float* wspf   = ktf + NF * 32;            // ~0.58M fl
    float* Sf     = wspf + 600000;            // S: NF*4096 bf16 = NF*2048 fl

    __bf16* h1t = (__bf16*)slabS1;            // (B,N,128)
    __bf16* h2t = (__bf16*)slabS2;            // (B,N,256)
    __bf16* h3t = (__bf16*)slabS1;            // (B,N,512)
    __bf16* h5t = (__bf16*)slabS2;            // (B,N,1024)
    float*  h4t = slabC;                      // (B,N,256) fp32
    __bf16* vb1 = (__bf16*)(slabC + NF * 256);// (B,256,N)
    float*  h6t = slabC;                      // (B,N,512) fp32
    __bf16* vb2 = (__bf16*)slabS1;            // (B,512,N)
    __bf16* qt  = (__bf16*)qtf;
    __bf16* ktb = (__bf16*)ktf;
    __bf16* wsp = (__bf16*)wspf;
    __bf16* Sbuf = (__bf16*)Sf;               // (B,4096,4096) bf16

    __bf16* wsL2  = wsp;            // 128*128
    __bf16* wsL3  = wsL2 + 16384;   // 256*256
    __bf16* wsL4  = wsL3 + 65536;   // 512*512
    __bf16* wsA1q = wsL4 + 262144;  // 32*512
    __bf16* wsA1k = wsA1q + 16384;
    __bf16* wsA1v = wsA1k + 16384;  // 256*512
    __bf16* wsA2q = wsA1v + 131072; // 64*1024
    __bf16* wsA2k = wsA2q + 65536;
    __bf16* wsA2v = wsA2k + 65536;  // 512*1024

    dim3 blk(256);

    SigP sp;
    sp.W[0] = W1; sp.u[0] = u1; sp.O[0] = 64;  sp.C[0] = 6;
    sp.W[1] = W2; sp.u[1] = u2; sp.O[1] = 128; sp.C[1] = 64;
    sp.W[2] = W3; sp.u[2] = u3; sp.O[2] = 256; sp.C[2] = 128;
    sp.W[3] = W4; sp.u[3] = u4; sp.O[3] = 512; sp.C[3] = 256;
    sp.W[4] = W5; sp.u[4] = u5; sp.O[4] = 1;   sp.C[4] = 512;
    sigma_all<<<dim3(5), dim3(1024), 0, stream>>>(sp, sig);

    wsplit_kernel<<<128, blk, 0, stream>>>(W2, sig + 1, 1.f, 64, wsL2);
    wsplit_kernel<<<256, blk, 0, stream>>>(W3, sig + 2, 1.f, 128, wsL3);
    wsplit_kernel<<<512, blk, 0, stream>>>(W4, sig + 3, 1.f, 256, wsL4);
    wsplit_kernel<<<32,  blk, 0, stream>>>(a1_qW, nullptr, LOG2E, 256, wsA1q);
    wsplit_kernel<<<32,  blk, 0, stream>>>(a1_kW, nullptr, 1.f, 256, wsA1k);
    wsplit_kernel<<<256, blk, 0, stream>>>(a1_vW, nullptr, 1.f, 256, wsA1v);
    wsplit_kernel<<<64,  blk, 0, stream>>>(a2_qW, nullptr, LOG2E, 512, wsA2q);
    wsplit_kernel<<<64,  blk, 0, stream>>>(a2_kW, nullptr, 1.f, 512, wsA2k);
    wsplit_kernel<<<512, blk, 0, stream>>>(a2_vW, nullptr, 1.f, 512, wsA2v);

    // L1 (fp32) + transpose/split
    conv_f32_kernel<<<dim3(64, 1, 4), blk, 0, stream>>>(x, W1, b1, sig + 0, h1, 6, 64, 1);
    tsplit64_kernel<<<dim3(64, 4), blk, 0, stream>>>(h1, h1t);

    // L2, L3 (split-MFMA)
    mfma_conv<4, 1, 2, 0, 1><<<dim3(32, 1, 4), blk, 0, stream>>>(h1t, wsL2, b2, 1.f, h2t, 64, 128);
    mfma_conv<4, 1, 2, 0, 1><<<dim3(32, 2, 4), blk, 0, stream>>>(h2t, wsL3, b3, 1.f, h3t, 128, 256);

    // attention 1 (C=256, Cq=32)
    mfma_conv<1, 4, 4, 0, 0><<<dim3(8, 1, 4), blk, 0, stream>>>(h3t, wsA1q, a1_qb, LOG2E, qt, 256, 32);
    mfma_conv<1, 4, 4, 0, 0><<<dim3(8, 1, 4), blk, 0, stream>>>(h3t, wsA1k, a1_kb, 1.f, ktb, 256, 32);
    mfma_conv<4, 1, 1, 0, 0><<<dim3(32, 2, 4), blk, 0, stream>>>(h3t, wsA1v, a1_vb, 1.f, vb1, 256, 256);
    s_gemm<32><<<dim3(32, 32, 4), blk, 0, stream>>>(qt, ktb, Sbuf);
    softmax_rows<<<dim3(4096), blk, 0, stream>>>(Sbuf);
    pv_gemm4<2><<<dim3(2048), blk, 0, stream>>>(Sbuf, vb1, h3t, a1_g, h4t, 256);

    // L4 (fp32-transposed input)
    mfma_conv<4, 1, 2, 1, 1><<<dim3(32, 4, 4), blk, 0, stream>>>(h4t, wsL4, b4, 1.f, h5t, 256, 512);

    // attention 2 (C=512, Cq=64)
    mfma_conv<2, 2, 4, 0, 0><<<dim3(16, 1, 4), blk, 0, stream>>>(h5t, wsA2q, a2_qb, LOG2E, qt, 512, 64);
    mfma_conv<2, 2, 4, 0, 0><<<dim3(16, 1, 4), blk, 0, stream>>>(h5t, wsA2k, a2_kb, 1.f, ktb, 512, 64);
    mfma_conv<4, 1, 1, 0, 0><<<dim3(32, 4, 4), blk, 0, stream>>>(h5t, wsA2v, a2_vb, 1.f, vb2, 512, 512);
    s_gemm<64><<<dim3(32, 32, 4), blk, 0, stream>>>(qt, ktb, Sbuf);
    softmax_rows<<<dim3(4096), blk, 0, stream>>>(Sbuf);
    pv_gemm4<4><<<dim3(2048), blk, 0, stream>>>(Sbuf, vb2, h5t, a2_g, h6t, 512);

    // L5
    l5_kernel<<<4096, blk, 0, stream>>>(h6t, W5, b5, sig + 4, (float*)d_out);
}

// Round 14
// 918.461 us; speedup vs baseline: 1.0660x; 1.0660x over previous
//
#include <hip/hip_runtime.h>
#include <math.h>

#define N_PIX 4096  // H*W = 64*64
#define BATCH 4
#define LOG2E 1.4426950408889634f

typedef __bf16 bf16x8 __attribute__((ext_vector_type(8)));
typedef __bf16 bf16x4v __attribute__((ext_vector_type(4)));
typedef float f32x4 __attribute__((ext_vector_type(4)));

// ---------------------------------------------------------------------------
// Fused spectral norms: one block per layer, 1024 threads (16 waves).
// ---------------------------------------------------------------------------
struct SigP {
    const float* W[5];
    const float* u[5];
    int O[5];
    int C[5];
};

__global__ __launch_bounds__(1024)
void sigma_all(SigP p, float* __restrict__ out_inv) {
    __shared__ float ush[512];
    __shared__ float vsh[512];
    __shared__ float vpart[16 * 512];
    __shared__ float redl[1024];
    int L = blockIdx.x;
    const float* W = p.W[L];
    const float* u = p.u[L];
    int O = p.O[L], C = p.C[L];
    int t = threadIdx.x;
    int w = t >> 6, lane = t & 63;

    for (int i = t; i < O; i += 1024) ush[i] = u[i];
    __syncthreads();

    int o_beg = (O * w) >> 4, o_end = (O * (w + 1)) >> 4;
    for (int c = lane; c < C; c += 64) {
        float a = 0.f;
        for (int o = o_beg; o < o_end; ++o) a += W[(size_t)o * C + c] * ush[o];
        vpart[w * 512 + c] = a;
    }
    __syncthreads();

    float nn = 0.f;
    for (int c = t; c < C; c += 1024) {
        float s = 0.f;
        #pragma unroll
        for (int w2 = 0; w2 < 16; ++w2) s += vpart[w2 * 512 + c];
        vsh[c] = s;
        nn += s * s;
    }
    redl[t] = nn;
    __syncthreads();
    for (int s = 512; s > 0; s >>= 1) {
        if (t < s) redl[t] += redl[t + s];
        __syncthreads();
    }
    float nrm2 = redl[0];
    __syncthreads();
    float rinv = 1.f / (sqrtf(nrm2) + 1e-12f);

    float sq = 0.f;
    for (int o = w; o < O; o += 16) {
        float a = 0.f;
        for (int c = lane; c < C; c += 64) a += W[(size_t)o * C + c] * vsh[c];
        #pragma unroll
        for (int off = 1; off < 64; off <<= 1) a += __shfl_xor(a, off);
        if (lane == 0) sq += a * a;
    }
    if (lane == 0) redl[w] = sq;
    __syncthreads();
    if (t == 0) {
        float ns2raw = 0.f;
        #pragma unroll
        for (int i = 0; i < 16; ++i) ns2raw += redl[i];
        float ns2 = rinv * rinv * ns2raw;
        float sg = ns2 / (sqrtf(ns2) + 1e-12f);
        out_inv[L] = 1.f / sg;
    }
}

// ---------------------------------------------------------------------------
// Weight split: (O,C) fp32 * iv * scale -> (O, 2C) bf16  [hi | lo].
// ---------------------------------------------------------------------------
__global__ __launch_bounds__(256)
void wsplit_kernel(const float* __restrict__ W, const float* __restrict__ iv,
                   float scale, int C, __bf16* __restrict__ out) {
    int o = blockIdx.x;
    float s = (iv ? iv[0] : 1.f) * scale;
    for (int c = threadIdx.x; c < C; c += 256) {
        float wv = W[(size_t)o * C + c] * s;
        __bf16 hi = (__bf16)wv;
        float lo = wv - (float)hi;
        out[(size_t)o * 2 * C + c] = hi;
        out[(size_t)o * 2 * C + C + c] = (__bf16)lo;
    }
}

// ---------------------------------------------------------------------------
// L1 only: fp32 VALU conv (C=6). x (B,C,N) -> out (B,O,N) fp32.
// ---------------------------------------------------------------------------
__global__ __launch_bounds__(256)
void conv_f32_kernel(const float* __restrict__ x, const float* __restrict__ W,
                     const float* __restrict__ bias, const float* __restrict__ sig,
                     float* __restrict__ out, int C, int O, int lrelu) {
    __shared__ float Ws[16][68];
    __shared__ float Xs[16][68];
    int t = threadIdx.x;
    int tx = t & 15, ty = t >> 4;
    int b = blockIdx.z;
    int n0 = blockIdx.x * 64, o0 = blockIdx.y * 64;
    float acc[4][4] = {};
    const float* xb = x + (size_t)b * C * N_PIX;
    for (int c0 = 0; c0 < C; c0 += 16) {
        #pragma unroll
        for (int i = 0; i < 4; ++i) {
            int e = t + i * 256;
            int o = e >> 4, c = e & 15;
            float wv = 0.f;
            if (o0 + o < O && c0 + c < C) wv = W[(size_t)(o0 + o) * C + c0 + c];
            Ws[c][o] = wv;
        }
        #pragma unroll
        for (int i = 0; i < 4; ++i) {
            int e = t + i * 256;
            int c = e >> 6, n = e & 63;
            float xv = 0.f;
            if (c0 + c < C) xv = xb[(size_t)(c0 + c) * N_PIX + n0 + n];
            Xs[c][n] = xv;
        }
        __syncthreads();
        #pragma unroll
        for (int cc = 0; cc < 16; ++cc) {
            float4 wv = *(const float4*)&Ws[cc][ty * 4];
            float4 xv = *(const float4*)&Xs[cc][tx * 4];
            float wa[4] = {wv.x, wv.y, wv.z, wv.w};
            float xa[4] = {xv.x, xv.y, xv.z, xv.w};
            #pragma unroll
            for (int i = 0; i < 4; ++i)
                #pragma unroll
                for (int j = 0; j < 4; ++j)
                    acc[i][j] += wa[i] * xa[j];
        }
        __syncthreads();
    }
    float ivv = sig ? sig[0] : 1.f;
    for (int i = 0; i < 4; ++i) {
        int o = o0 + ty * 4 + i;
        if (o >= O) break;
        float bv = bias[o];
        float vres[4];
        #pragma unroll
        for (int j = 0; j < 4; ++j) {
            float v = acc[i][j] * ivv + bv;
            if (lrelu) v = (v > 0.f) ? v : 0.1f * v;
            vres[j] = v;
        }
        *(float4*)&out[((size_t)b * O + o) * N_PIX + n0 + tx * 4] =
            make_float4(vres[0], vres[1], vres[2], vres[3]);
    }
}

// ---------------------------------------------------------------------------
// Transpose+split: (B,64,N) fp32 -> (B,N,128) bf16 [hi(64)|lo(64)].
// ---------------------------------------------------------------------------
__global__ __launch_bounds__(256)
void tsplit64_kernel(const float* __restrict__ in, __bf16* __restrict__ out) {
    __shared__ float tile[64 * 65];
    int t = threadIdx.x;
    int n0 = blockIdx.x * 64, b = blockIdx.y;
    for (int e = t; e < 64 * 64; e += 256) {
        int c = e >> 6, n = e & 63;
        tile[n * 65 + c] = in[((size_t)b * 64 + c) * N_PIX + n0 + n];
    }
    __syncthreads();
    for (int e = t; e < 64 * 64; e += 256) {
        int n = e >> 6, c = e & 63;
        float v = tile[n * 65 + c];
        __bf16 hi = (__bf16)v;
        size_t base = ((size_t)b * N_PIX + n0 + n) * 128;
        out[base + c] = hi;
        out[base + 64 + c] = (__bf16)(v - (float)hi);
    }
}

// ---------------------------------------------------------------------------
// Split-bf16 MFMA 1x1 conv (unchanged).
// ---------------------------------------------------------------------------
template <int WO, int WN, int MODE, int IN_F32, int LRELU>
__global__ __launch_bounds__(256)
void mfma_conv(const void* __restrict__ xt, const __bf16* __restrict__ wsp,
               const float* __restrict__ bias, float bscale,
               void* __restrict__ outp, int C, int O) {
    constexpr int NT_BLK = WN * 128;
    __shared__ __bf16 Ws[WO * 32 * 72];
    __shared__ __bf16 Xs[NT_BLK * 72];
    int t = threadIdx.x;
    int lane = t & 63, w = t >> 6;
    int l15 = lane & 15, quad = lane >> 4;
    int wo = w / WN, wn = w % WN;
    int b = blockIdx.z;
    int n0b = blockIdx.x * NT_BLK, o0b = blockIdx.y * WO * 32;

    f32x4 acc[2][8] = {};

    for (int c0 = 0; c0 < C; c0 += 32) {
        __syncthreads();
        for (int e = t; e < WO * 32 * 8; e += 256) {
            int row = e >> 3, part = e & 7;
            size_t src = (size_t)(o0b + row) * 2 * C +
                         (part < 4 ? c0 + part * 8 : C + c0 + (part - 4) * 8);
            int dst = row * 72 + (part < 4 ? part * 8 : 32 + (part - 4) * 8);
            *(uint4*)&Ws[dst] = *(const uint4*)&wsp[src];
        }
        if (IN_F32) {
            const float* xf = (const float*)xt;
            for (int e = t; e < NT_BLK * 8; e += 256) {
                int row = e >> 3, part = e & 7;
                float4 v = *(const float4*)&xf[((size_t)b * N_PIX + n0b + row) * C + c0 + part * 4];
                bf16x4v hi, lo;
                float va[4] = {v.x, v.y, v.z, v.w};
                #pragma unroll
                for (int j = 0; j < 4; ++j) {
                    hi[j] = (__bf16)va[j];
                    lo[j] = (__bf16)(va[j] - (float)hi[j]);
                }
                *(bf16x4v*)&Xs[row * 72 + part * 4] = hi;
                *(bf16x4v*)&Xs[row * 72 + 32 + part * 4] = lo;
            }
        } else {
            const __bf16* xb = (const __bf16*)xt;
            for (int e = t; e < NT_BLK * 8; e += 256) {
                int row = e >> 3, part = e & 7;
                size_t src = ((size_t)b * N_PIX + n0b + row) * 2 * C +
                             (part < 4 ? c0 + part * 8 : C + c0 + (part - 4) * 8);
                int dst = row * 72 + (part < 4 ? part * 8 : 32 + (part - 4) * 8);
                *(uint4*)&Xs[dst] = *(const uint4*)&xb[src];
            }
        }
        __syncthreads();

        bf16x8 ah[2], al[2];
        #pragma unroll
        for (int mf = 0; mf < 2; ++mf) {
            int base = (wo * 32 + mf * 16 + l15) * 72 + quad * 8;
            ah[mf] = *(const bf16x8*)&Ws[base];
            al[mf] = *(const bf16x8*)&Ws[base + 32];
        }
        #pragma unroll
        for (int nt = 0; nt < 8; ++nt) {
            int bbase = (wn * 128 + nt * 16 + l15) * 72 + quad * 8;
            bf16x8 bh = *(const bf16x8*)&Xs[bbase];
            bf16x8 bl = *(const bf16x8*)&Xs[bbase + 32];
            #pragma unroll
            for (int mf = 0; mf < 2; ++mf) {
                acc[mf][nt] = __builtin_amdgcn_mfma_f32_16x16x32_bf16(ah[mf], bh, acc[mf][nt], 0, 0, 0);
                acc[mf][nt] = __builtin_amdgcn_mfma_f32_16x16x32_bf16(ah[mf], bl, acc[mf][nt], 0, 0, 0);
                acc[mf][nt] = __builtin_amdgcn_mfma_f32_16x16x32_bf16(al[mf], bh, acc[mf][nt], 0, 0, 0);
            }
        }
    }

    float bv[2][4];
    #pragma unroll
    for (int mf = 0; mf < 2; ++mf)
        #pragma unroll
        for (int r = 0; r < 4; ++r)
            bv[mf][r] = bias[o0b + wo * 32 + mf * 16 + quad * 4 + r] * bscale;

    #pragma unroll
    for (int mf = 0; mf < 2; ++mf)
        #pragma unroll
        for (int nt = 0; nt < 8; ++nt) {
            int n = n0b + wn * 128 + nt * 16 + l15;
            float val[4];
            #pragma unroll
            for (int r = 0; r < 4; ++r) {
                float v = acc[mf][nt][r] + bv[mf][r];
                if (LRELU) v = (v > 0.f) ? v : 0.1f * v;
                val[r] = v;
            }
            int obase = o0b + wo * 32 + mf * 16 + quad * 4;
            if (MODE == 1) {
                __bf16* ob = (__bf16*)outp;
                #pragma unroll
                for (int r = 0; r < 4; ++r)
                    ob[((size_t)b * O + obase + r) * N_PIX + n] = (__bf16)val[r];
            } else if (MODE == 2) {
                __bf16* ob = (__bf16*)outp;
                bf16x4v hv, lv;
                #pragma unroll
                for (int r = 0; r < 4; ++r) {
                    hv[r] = (__bf16)val[r];
                    lv[r] = (__bf16)(val[r] - (float)hv[r]);
                }
                size_t rb = ((size_t)b * N_PIX + n) * 2 * O + obase;
                *(bf16x4v*)&ob[rb] = hv;
                *(bf16x4v*)&ob[rb + O] = lv;
            } else {  // MODE 4
                __bf16* ob = (__bf16*)outp;
                bf16x4v hv;
                #pragma unroll
                for (int r = 0; r < 4; ++r) hv[r] = (__bf16)val[r];
                *(bf16x4v*)&ob[((size_t)b * N_PIX + n) * O + obase] = hv;
            }
        }
}

// ---------------------------------------------------------------------------
// Attention kernel 1/3: E[b,q,k] = exp2(sum_c kt[b,k,c]*qt[b,q,c]), bf16.
// Unnormalized softmax numerator (qt pre-scaled by log2e). End-normalization
// makes the max-shift unnecessary: out = (Σ E·V)/(Σ E) is exact in exact
// arithmetic; fp32/bf16 exponent range absorbs unshifted exp2 (|s_log2|<~120).
// ---------------------------------------------------------------------------
template <int CQ>
__global__ __launch_bounds__(256)
void s_gemm(const __bf16* __restrict__ qt, const __bf16* __restrict__ kt,
            __bf16* __restrict__ S) {
    constexpr int NKK = CQ / 32;
    __shared__ __bf16 Ss[128 * 136];
    int t = threadIdx.x;
    int lane = t & 63, w = t >> 6;
    int l15 = lane & 15, quad = lane >> 4;
    int k0 = blockIdx.x * 128, q0 = blockIdx.y * 128, b = blockIdx.z;

    bf16x8 kf[2][NKK], qf[8][NKK];
    #pragma unroll
    for (int mf = 0; mf < 2; ++mf)
        #pragma unroll
        for (int kk = 0; kk < NKK; ++kk)
            kf[mf][kk] = *(const bf16x8*)&kt[((size_t)b * N_PIX + k0 + w * 32 + mf * 16 + l15) * CQ + kk * 32 + quad * 8];
    #pragma unroll
    for (int nt = 0; nt < 8; ++nt)
        #pragma unroll
        for (int kk = 0; kk < NKK; ++kk)
            qf[nt][kk] = *(const bf16x8*)&qt[((size_t)b * N_PIX + q0 + nt * 16 + l15) * CQ + kk * 32 + quad * 8];

    f32x4 acc[2][8] = {};
    #pragma unroll
    for (int kk = 0; kk < NKK; ++kk)
        #pragma unroll
        for (int mf = 0; mf < 2; ++mf)
            #pragma unroll
            for (int nt = 0; nt < 8; ++nt)
                acc[mf][nt] = __builtin_amdgcn_mfma_f32_16x16x32_bf16(kf[mf][kk], qf[nt][kk], acc[mf][nt], 0, 0, 0);

    #pragma unroll
    for (int mf = 0; mf < 2; ++mf)
        #pragma unroll
        for (int nt = 0; nt < 8; ++nt) {
            bf16x4v pk;
            #pragma unroll
            for (int r = 0; r < 4; ++r) pk[r] = (__bf16)exp2f(acc[mf][nt][r]);
            *(bf16x4v*)&Ss[(nt * 16 + l15) * 136 + w * 32 + mf * 16 + quad * 4] = pk;
        }
    __syncthreads();
    int ql = t >> 1, kh = (t & 1) * 64;
    size_t row = ((size_t)b * N_PIX + q0 + ql) * N_PIX + k0 + kh;
    #pragma unroll
    for (int j = 0; j < 8; ++j)
        *(uint4*)&S[row + j * 8] = *(const uint4*)&Ss[ql * 136 + kh + j * 8];
}

// ---------------------------------------------------------------------------
// Attention kernel 2/3: per-row sum of E -> il = 1/sum. READ-ONLY pass
// (replaces the read-modify-write softmax; normalization folded into pv).
// One wave per 4096-key row; 4 rows/block.
// ---------------------------------------------------------------------------
__global__ __launch_bounds__(256)
void row_sum(const __bf16* __restrict__ E, float* __restrict__ il) {
    int t = threadIdx.x;
    int lane = t & 63, w = t >> 6;
    size_t row = (size_t)blockIdx.x * 4 + w;
    const __bf16* Er = E + row * N_PIX;
    float s = 0.f;
    #pragma unroll
    for (int j = 0; j < 8; ++j) {
        bf16x8 v = *(const bf16x8*)&Er[j * 512 + lane * 8];
        #pragma unroll
        for (int e = 0; e < 8; ++e) s += (float)v[e];
    }
    #pragma unroll
    for (int off = 1; off < 64; off <<= 1) s += __shfl_xor(s, off);
    if (lane == 0) il[row] = 1.f / s;
}

// ---------------------------------------------------------------------------
// Attention kernel 3/3: LDS-staged PV GEMM (R12 config: M=128, grid 1024).
// O[b,q,c] = gamma * il[q] * sum_k E[b,q,k] V[b,c,k] + residual.
// Block: 128 q x NT*16 c.  Grid 1024 = 8 cblk x 128 pair; bid%8 == pair%8
// pins all 8 c-block sharers of one (q0,b) E-slab to one XCD (L2 reuse).
// ---------------------------------------------------------------------------
template <int NT>
__global__ __launch_bounds__(256)
void pv_gemm5(const __bf16* __restrict__ E, const __bf16* __restrict__ vg,
              const float* __restrict__ il, const __bf16* __restrict__ xin2,
              const float* __restrict__ gamma, float* __restrict__ out, int C) {
    constexpr int CCH = NT * 16;
    __shared__ __bf16 Psh[128 * 72];
    __shared__ __bf16 Vsh[CCH * 72];
    __shared__ float ilsh[128];
    int t = threadIdx.x;
    int lane = t & 63, w = t >> 6;
    int l15 = lane & 15, quad = lane >> 4;
    int bid = blockIdx.x;
    int pair = bid & 127, cblk = bid >> 7;
    int qi = pair >> 2, b = pair & 3;
    int q0 = qi * 128, c0 = cblk * CCH;
    const __bf16* Pb = E + ((size_t)b * N_PIX + q0) * N_PIX;
    const __bf16* Vb = vg + ((size_t)b * C + c0) * N_PIX;

    if (t < 128) ilsh[t] = il[(size_t)b * N_PIX + q0 + t];

    f32x4 acc[2][NT] = {};

    for (int k0 = 0; k0 < N_PIX; k0 += 64) {
        __syncthreads();
        #pragma unroll
        for (int i = 0; i < 4; ++i) {  // E tile: 128 q-rows x 64 k
            int e = t + i * 256;
            int row = e >> 3, seg = e & 7;
            *(uint4*)&Psh[row * 72 + seg * 8] = *(const uint4*)&Pb[(size_t)row * N_PIX + k0 + seg * 8];
        }
        for (int e = t; e < CCH * 8; e += 256) {  // V tile: CCH c-rows x 64 k
            int row = e >> 3, seg = e & 7;
            *(uint4*)&Vsh[row * 72 + seg * 8] = *(const uint4*)&Vb[(size_t)row * N_PIX + k0 + seg * 8];
        }
        __syncthreads();
        #pragma unroll
        for (int kk = 0; kk < 2; ++kk) {
            bf16x8 pa[2];
            #pragma unroll
            for (int mf = 0; mf < 2; ++mf)
                pa[mf] = *(const bf16x8*)&Psh[(w * 32 + mf * 16 + l15) * 72 + kk * 32 + quad * 8];
            #pragma unroll
            for (int nt = 0; nt < NT; ++nt) {
                bf16x8 vf = *(const bf16x8*)&Vsh[(nt * 16 + l15) * 72 + kk * 32 + quad * 8];
                #pragma unroll
                for (int mf = 0; mf < 2; ++mf)
                    acc[mf][nt] = __builtin_amdgcn_mfma_f32_16x16x32_bf16(pa[mf], vf, acc[mf][nt], 0, 0, 0);
            }
        }
    }

    float g = gamma[0];
    #pragma unroll
    for (int mf = 0; mf < 2; ++mf)
        #pragma unroll
        for (int r = 0; r < 4; ++r) {
            int ql = w * 32 + mf * 16 + quad * 4 + r;
            int q = q0 + ql;
            float gil = g * ilsh[ql];
            size_t xrb = ((size_t)b * N_PIX + q) * 2 * C;
            size_t orb = ((size_t)b * N_PIX + q) * C;
            #pragma unroll
            for (int nt = 0; nt < NT; ++nt) {
                int c = c0 + nt * 16 + l15;
                float xr = (float)xin2[xrb + c] + (float)xin2[xrb + C + c];
                out[orb + c] = gil * acc[mf][nt][r] + xr;
            }
        }
}

// ---------------------------------------------------------------------------
// L5: out[b,n] = lrelu(iv * dot(W5, h[b,n,:]) + b5).  h: (B,N,512) fp32.
// ---------------------------------------------------------------------------
__global__ __launch_bounds__(256)
void l5_kernel(const float* __restrict__ h, const float* __restrict__ W5,
               const float* __restrict__ b5, const float* __restrict__ sig,
               float* __restrict__ out) {
    int t = threadIdx.x;
    int lane = t & 63, w = t >> 6;
    int p = blockIdx.x * 4 + w;
    const float* row = h + (size_t)p * 512;
    float4 a0 = *(const float4*)&row[lane * 8];
    float4 a1 = *(const float4*)&row[lane * 8 + 4];
    float4 w0 = *(const float4*)&W5[lane * 8];
    float4 w1 = *(const float4*)&W5[lane * 8 + 4];
    float s = a0.x * w0.x + a0.y * w0.y + a0.z * w0.z + a0.w * w0.w +
              a1.x * w1.x + a1.y * w1.y + a1.z * w1.z + a1.w * w1.w;
    #pragma unroll
    for (int off = 1; off < 64; off <<= 1) s += __shfl_xor(s, off);
    if (lane == 0) {
        float v = sig[0] * s + b5[0];
        out[p] = (v > 0.f) ? v : 0.1f * v;
    }
}

// ---------------------------------------------------------------------------
// Launcher
// ---------------------------------------------------------------------------
extern "C" void kernel_launch(void* const* d_in, const int* in_sizes, int n_in,
                              void* d_out, int out_size, void* d_ws, size_t ws_size,
                              hipStream_t stream) {
    const float* x   = (const float*)d_in[0];
    const float* W1  = (const float*)d_in[1];
    const float* b1  = (const float*)d_in[2];
    const float* u1  = (const float*)d_in[3];
    const float* W2  = (const float*)d_in[4];
    const float* b2  = (const float*)d_in[5];
    const float* u2  = (const float*)d_in[6];
    const float* W3  = (const float*)d_in[7];
    const float* b3  = (const float*)d_in[8];
    const float* u3  = (const float*)d_in[9];
    const float* W4  = (const float*)d_in[10];
    const float* b4  = (const float*)d_in[11];
    const float* u4  = (const float*)d_in[12];
    const float* W5  = (const float*)d_in[13];
    const float* b5  = (const float*)d_in[14];
    const float* u5  = (const float*)d_in[15];
    const float* a1_qW = (const float*)d_in[16];
    const float* a1_qb = (const float*)d_in[17];
    const float* a1_kW = (const float*)d_in[18];
    const float* a1_kb = (const float*)d_in[19];
    const float* a1_vW = (const float*)d_in[20];
    const float* a1_vb = (const float*)d_in[21];
    const float* a1_g  = (const float*)d_in[22];
    const float* a2_qW = (const float*)d_in[23];
    const float* a2_qb = (const float*)d_in[24];
    const float* a2_kW = (const float*)d_in[25];
    const float* a2_kb = (const float*)d_in[26];
    const float* a2_vW = (const float*)d_in[27];
    const float* a2_vb = (const float*)d_in[28];
    const float* a2_g  = (const float*)d_in[29];

    float* ws = (float*)d_ws;
    const size_t NF = (size_t)BATCH * N_PIX;  // 16384
    float* sig    = ws;                       // 16
    float* h1     = ws + 16;                  // NF*64 fl (reused as il stats)
    float* slabC  = h1 + NF * 64;             // NF*512 fl
    float* slabS1 = slabC + NF * 512;         // NF*256 fl
    float* slabS2 = slabS1 + NF * 256;        // NF*512 fl
    float* qtf    = slabS2 + NF * 512;        // NF*32 fl
    float* ktf    = qtf + NF * 32;            // NF*32 fl
    float* wspf   = ktf + NF * 32;            // ~0.58M fl
    float* Sf     = wspf + 600000;            // E: NF*4096 bf16 = NF*2048 fl

    __bf16* h1t = (__bf16*)slabS1;            // (B,N,128)
    __bf16* h2t = (__bf16*)slabS2;            // (B,N,256)
    __bf16* h3t = (__bf16*)slabS1;            // (B,N,512)
    __bf16* h5t = (__bf16*)slabS2;            // (B,N,1024)
    float*  h4t = slabC;                      // (B,N,256) fp32
    __bf16* vb1 = (__bf16*)(slabC + NF * 256);// (B,256,N)
    float*  h6t = slabC;                      // (B,N,512) fp32
    __bf16* vb2 = (__bf16*)slabS1;            // (B,512,N)
    __bf16* qt  = (__bf16*)qtf;
    __bf16* ktb = (__bf16*)ktf;
    __bf16* wsp = (__bf16*)wspf;
    __bf16* Sbuf = (__bf16*)Sf;               // (B,4096,4096) bf16
    float*  ilbuf = h1;                       // B*N floats (h1 dead after tsplit)

    __bf16* wsL2  = wsp;            // 128*128
    __bf16* wsL3  = wsL2 + 16384;   // 256*256
    __bf16* wsL4  = wsL3 + 65536;   // 512*512
    __bf16* wsA1q = wsL4 + 262144;  // 32*512
    __bf16* wsA1k = wsA1q + 16384;
    __bf16* wsA1v = wsA1k + 16384;  // 256*512
    __bf16* wsA2q = wsA1v + 131072; // 64*1024
    __bf16* wsA2k = wsA2q + 65536;
    __bf16* wsA2v = wsA2k + 65536;  // 512*1024

    dim3 blk(256);

    SigP sp;
    sp.W[0] = W1; sp.u[0] = u1; sp.O[0] = 64;  sp.C[0] = 6;
    sp.W[1] = W2; sp.u[1] = u2; sp.O[1] = 128; sp.C[1] = 64;
    sp.W[2] = W3; sp.u[2] = u3; sp.O[2] = 256; sp.C[2] = 128;
    sp.W[3] = W4; sp.u[3] = u4; sp.O[3] = 512; sp.C[3] = 256;
    sp.W[4] = W5; sp.u[4] = u5; sp.O[4] = 1;   sp.C[4] = 512;
    sigma_all<<<dim3(5), dim3(1024), 0, stream>>>(sp, sig);

    wsplit_kernel<<<128, blk, 0, stream>>>(W2, sig + 1, 1.f, 64, wsL2);
    wsplit_kernel<<<256, blk, 0, stream>>>(W3, sig + 2, 1.f, 128, wsL3);
    wsplit_kernel<<<512, blk, 0, stream>>>(W4, sig + 3, 1.f, 256, wsL4);
    wsplit_kernel<<<32,  blk, 0, stream>>>(a1_qW, nullptr, LOG2E, 256, wsA1q);
    wsplit_kernel<<<32,  blk, 0, stream>>>(a1_kW, nullptr, 1.f, 256, wsA1k);
    wsplit_kernel<<<256, blk, 0, stream>>>(a1_vW, nullptr, 1.f, 256, wsA1v);
    wsplit_kernel<<<64,  blk, 0, stream>>>(a2_qW, nullptr, LOG2E, 512, wsA2q);
    wsplit_kernel<<<64,  blk, 0, stream>>>(a2_kW, nullptr, 1.f, 512, wsA2k);
    wsplit_kernel<<<512, blk, 0, stream>>>(a2_vW, nullptr, 1.f, 512, wsA2v);

    // L1 (fp32) + transpose/split
    conv_f32_kernel<<<dim3(64, 1, 4), blk, 0, stream>>>(x, W1, b1, sig + 0, h1, 6, 64, 1);
    tsplit64_kernel<<<dim3(64, 4), blk, 0, stream>>>(h1, h1t);

    // L2, L3 (split-MFMA)
    mfma_conv<4, 1, 2, 0, 1><<<dim3(32, 1, 4), blk, 0, stream>>>(h1t, wsL2, b2, 1.f, h2t, 64, 128);
    mfma_conv<4, 1, 2, 0, 1><<<dim3(32, 2, 4), blk, 0, stream>>>(h2t, wsL3, b3, 1.f, h3t, 128, 256);

    // attention 1 (C=256, Cq=32)
    mfma_conv<1, 4, 4, 0, 0><<<dim3(8, 1, 4), blk, 0, stream>>>(h3t, wsA1q, a1_qb, LOG2E, qt, 256, 32);
    mfma_conv<1, 4, 4, 0, 0><<<dim3(8, 1, 4), blk, 0, stream>>>(h3t, wsA1k, a1_kb, 1.f, ktb, 256, 32);
    mfma_conv<4, 1, 1, 0, 0><<<dim3(32, 2, 4), blk, 0, stream>>>(h3t, wsA1v, a1_vb, 1.f, vb1, 256, 256);
    s_gemm<32><<<dim3(32, 32, 4), blk, 0, stream>>>(qt, ktb, Sbuf);
    row_sum<<<dim3(4096), blk, 0, stream>>>(Sbuf, ilbuf);
    pv_gemm5<2><<<dim3(1024), blk, 0, stream>>>(Sbuf, vb1, ilbuf, h3t, a1_g, h4t, 256);

    // L4 (fp32-transposed input)
    mfma_conv<4, 1, 2, 1, 1><<<dim3(32, 4, 4), blk, 0, stream>>>(h4t, wsL4, b4, 1.f, h5t, 256, 512);

    // attention 2 (C=512, Cq=64)
    mfma_conv<2, 2, 4, 0, 0><<<dim3(16, 1, 4), blk, 0, stream>>>(h5t, wsA2q, a2_qb, LOG2E, qt, 512, 64);
    mfma_conv<2, 2, 4, 0, 0><<<dim3(16, 1, 4), blk, 0, stream>>>(h5t, wsA2k, a2_kb, 1.f, ktb, 512, 64);
    mfma_conv<4, 1, 1, 0, 0><<<dim3(32, 4, 4), blk, 0, stream>>>(h5t, wsA2v, a2_vb, 1.f, vb2, 512, 512);
    s_gemm<64><<<dim3(32, 32, 4), blk, 0, stream>>>(qt, ktb, Sbuf);
    row_sum<<<dim3(4096), blk, 0, stream>>>(Sbuf, ilbuf);
    pv_gemm5<4><<<dim3(1024), blk, 0, stream>>>(Sbuf, vb2, ilbuf, h5t, a2_g, h6t, 512);

    // L5
    l5_kernel<<<4096, blk, 0, stream>>>(h6t, W5, b5, sig + 4, (float*)d_out);
}

// Round 15
// 816.369 us; speedup vs baseline: 1.1993x; 1.1251x over previous
//
#include <hip/hip_runtime.h>
#include <math.h>

#define N_PIX 4096  // H*W = 64*64
#define BATCH 4
#define LOG2E 1.4426950408889634f

typedef __bf16 bf16x8 __attribute__((ext_vector_type(8)));
typedef __bf16 bf16x4v __attribute__((ext_vector_type(4)));
typedef float f32x4 __attribute__((ext_vector_type(4)));

// ---------------------------------------------------------------------------
// Fused spectral norms: one block per layer, 1024 threads (16 waves).
// ---------------------------------------------------------------------------
struct SigP {
    const float* W[5];
    const float* u[5];
    int O[5];
    int C[5];
};

__global__ __launch_bounds__(1024)
void sigma_all(SigP p, float* __restrict__ out_inv) {
    __shared__ float ush[512];
    __shared__ float vsh[512];
    __shared__ float vpart[16 * 512];
    __shared__ float redl[1024];
    int L = blockIdx.x;
    const float* W = p.W[L];
    const float* u = p.u[L];
    int O = p.O[L], C = p.C[L];
    int t = threadIdx.x;
    int w = t >> 6, lane = t & 63;

    for (int i = t; i < O; i += 1024) ush[i] = u[i];
    __syncthreads();

    int o_beg = (O * w) >> 4, o_end = (O * (w + 1)) >> 4;
    for (int c = lane; c < C; c += 64) {
        float a = 0.f;
        for (int o = o_beg; o < o_end; ++o) a += W[(size_t)o * C + c] * ush[o];
        vpart[w * 512 + c] = a;
    }
    __syncthreads();

    float nn = 0.f;
    for (int c = t; c < C; c += 1024) {
        float s = 0.f;
        #pragma unroll
        for (int w2 = 0; w2 < 16; ++w2) s += vpart[w2 * 512 + c];
        vsh[c] = s;
        nn += s * s;
    }
    redl[t] = nn;
    __syncthreads();
    for (int s = 512; s > 0; s >>= 1) {
        if (t < s) redl[t] += redl[t + s];
        __syncthreads();
    }
    float nrm2 = redl[0];
    __syncthreads();
    float rinv = 1.f / (sqrtf(nrm2) + 1e-12f);

    float sq = 0.f;
    for (int o = w; o < O; o += 16) {
        float a = 0.f;
        for (int c = lane; c < C; c += 64) a += W[(size_t)o * C + c] * vsh[c];
        #pragma unroll
        for (int off = 1; off < 64; off <<= 1) a += __shfl_xor(a, off);
        if (lane == 0) sq += a * a;
    }
    if (lane == 0) redl[w] = sq;
    __syncthreads();
    if (t == 0) {
        float ns2raw = 0.f;
        #pragma unroll
        for (int i = 0; i < 16; ++i) ns2raw += redl[i];
        float ns2 = rinv * rinv * ns2raw;
        float sg = ns2 / (sqrtf(ns2) + 1e-12f);
        out_inv[L] = 1.f / sg;
    }
}

// ---------------------------------------------------------------------------
// Weight split: (O,C) fp32 * iv * scale -> (O, 2C) bf16  [hi | lo].
// ---------------------------------------------------------------------------
__global__ __launch_bounds__(256)
void wsplit_kernel(const float* __restrict__ W, const float* __restrict__ iv,
                   float scale, int C, __bf16* __restrict__ out) {
    int o = blockIdx.x;
    float s = (iv ? iv[0] : 1.f) * scale;
    for (int c = threadIdx.x; c < C; c += 256) {
        float wv = W[(size_t)o * C + c] * s;
        __bf16 hi = (__bf16)wv;
        float lo = wv - (float)hi;
        out[(size_t)o * 2 * C + c] = hi;
        out[(size_t)o * 2 * C + C + c] = (__bf16)lo;
    }
}

// ---------------------------------------------------------------------------
// Concat + prescale attention projection biases:
// bb[0:64]   = [a1_qb*log2e | a1_kb]
// bb[64:192] = [a2_qb*log2e | a2_kb]
// ---------------------------------------------------------------------------
__global__ __launch_bounds__(256)
void concat_bias(const float* __restrict__ qb1, const float* __restrict__ kb1,
                 const float* __restrict__ qb2, const float* __restrict__ kb2,
                 float* __restrict__ bb) {
    int t = threadIdx.x;
    if (t < 32) bb[t] = qb1[t] * LOG2E;
    else if (t < 64) bb[t] = kb1[t - 32];
    else if (t < 128) bb[t] = qb2[t - 64] * LOG2E;
    else if (t < 192) bb[t] = kb2[t - 128];
}

// ---------------------------------------------------------------------------
// L1 only: fp32 VALU conv (C=6). x (B,C,N) -> out (B,O,N) fp32.
// ---------------------------------------------------------------------------
__global__ __launch_bounds__(256)
void conv_f32_kernel(const float* __restrict__ x, const float* __restrict__ W,
                     const float* __restrict__ bias, const float* __restrict__ sig,
                     float* __restrict__ out, int C, int O, int lrelu) {
    __shared__ float Ws[16][68];
    __shared__ float Xs[16][68];
    int t = threadIdx.x;
    int tx = t & 15, ty = t >> 4;
    int b = blockIdx.z;
    int n0 = blockIdx.x * 64, o0 = blockIdx.y * 64;
    float acc[4][4] = {};
    const float* xb = x + (size_t)b * C * N_PIX;
    for (int c0 = 0; c0 < C; c0 += 16) {
        #pragma unroll
        for (int i = 0; i < 4; ++i) {
            int e = t + i * 256;
            int o = e >> 4, c = e & 15;
            float wv = 0.f;
            if (o0 + o < O && c0 + c < C) wv = W[(size_t)(o0 + o) * C + c0 + c];
            Ws[c][o] = wv;
        }
        #pragma unroll
        for (int i = 0; i < 4; ++i) {
            int e = t + i * 256;
            int c = e >> 6, n = e & 63;
            float xv = 0.f;
            if (c0 + c < C) xv = xb[(size_t)(c0 + c) * N_PIX + n0 + n];
            Xs[c][n] = xv;
        }
        __syncthreads();
        #pragma unroll
        for (int cc = 0; cc < 16; ++cc) {
            float4 wv = *(const float4*)&Ws[cc][ty * 4];
            float4 xv = *(const float4*)&Xs[cc][tx * 4];
            float wa[4] = {wv.x, wv.y, wv.z, wv.w};
            float xa[4] = {xv.x, xv.y, xv.z, xv.w};
            #pragma unroll
            for (int i = 0; i < 4; ++i)
                #pragma unroll
                for (int j = 0; j < 4; ++j)
                    acc[i][j] += wa[i] * xa[j];
        }
        __syncthreads();
    }
    float ivv = sig ? sig[0] : 1.f;
    for (int i = 0; i < 4; ++i) {
        int o = o0 + ty * 4 + i;
        if (o >= O) break;
        float bv = bias[o];
        float vres[4];
        #pragma unroll
        for (int j = 0; j < 4; ++j) {
            float v = acc[i][j] * ivv + bv;
            if (lrelu) v = (v > 0.f) ? v : 0.1f * v;
            vres[j] = v;
        }
        *(float4*)&out[((size_t)b * O + o) * N_PIX + n0 + tx * 4] =
            make_float4(vres[0], vres[1], vres[2], vres[3]);
    }
}

// ---------------------------------------------------------------------------
// Transpose+split: (B,64,N) fp32 -> (B,N,128) bf16 [hi(64)|lo(64)].
// ---------------------------------------------------------------------------
__global__ __launch_bounds__(256)
void tsplit64_kernel(const float* __restrict__ in, __bf16* __restrict__ out) {
    __shared__ float tile[64 * 65];
    int t = threadIdx.x;
    int n0 = blockIdx.x * 64, b = blockIdx.y;
    for (int e = t; e < 64 * 64; e += 256) {
        int c = e >> 6, n = e & 63;
        tile[n * 65 + c] = in[((size_t)b * 64 + c) * N_PIX + n0 + n];
    }
    __syncthreads();
    for (int e = t; e < 64 * 64; e += 256) {
        int n = e >> 6, c = e & 63;
        float v = tile[n * 65 + c];
        __bf16 hi = (__bf16)v;
        size_t base = ((size_t)b * N_PIX + n0 + n) * 128;
        out[base + c] = hi;
        out[base + 64 + c] = (__bf16)(v - (float)hi);
    }
}

// ---------------------------------------------------------------------------
// Split-bf16 MFMA 1x1 conv (unchanged).
// ---------------------------------------------------------------------------
template <int WO, int WN, int MODE, int IN_F32, int LRELU>
__global__ __launch_bounds__(256)
void mfma_conv(const void* __restrict__ xt, const __bf16* __restrict__ wsp,
               const float* __restrict__ bias, float bscale,
               void* __restrict__ outp, int C, int O) {
    constexpr int NT_BLK = WN * 128;
    __shared__ __bf16 Ws[WO * 32 * 72];
    __shared__ __bf16 Xs[NT_BLK * 72];
    int t = threadIdx.x;
    int lane = t & 63, w = t >> 6;
    int l15 = lane & 15, quad = lane >> 4;
    int wo = w / WN, wn = w % WN;
    int b = blockIdx.z;
    int n0b = blockIdx.x * NT_BLK, o0b = blockIdx.y * WO * 32;

    f32x4 acc[2][8] = {};

    for (int c0 = 0; c0 < C; c0 += 32) {
        __syncthreads();
        for (int e = t; e < WO * 32 * 8; e += 256) {
            int row = e >> 3, part = e & 7;
            size_t src = (size_t)(o0b + row) * 2 * C +
                         (part < 4 ? c0 + part * 8 : C + c0 + (part - 4) * 8);
            int dst = row * 72 + (part < 4 ? part * 8 : 32 + (part - 4) * 8);
            *(uint4*)&Ws[dst] = *(const uint4*)&wsp[src];
        }
        if (IN_F32) {
            const float* xf = (const float*)xt;
            for (int e = t; e < NT_BLK * 8; e += 256) {
                int row = e >> 3, part = e & 7;
                float4 v = *(const float4*)&xf[((size_t)b * N_PIX + n0b + row) * C + c0 + part * 4];
                bf16x4v hi, lo;
                float va[4] = {v.x, v.y, v.z, v.w};
                #pragma unroll
                for (int j = 0; j < 4; ++j) {
                    hi[j] = (__bf16)va[j];
                    lo[j] = (__bf16)(va[j] - (float)hi[j]);
                }
                *(bf16x4v*)&Xs[row * 72 + part * 4] = hi;
                *(bf16x4v*)&Xs[row * 72 + 32 + part * 4] = lo;
            }
        } else {
            const __bf16* xb = (const __bf16*)xt;
            for (int e = t; e < NT_BLK * 8; e += 256) {
                int row = e >> 3, part = e & 7;
                size_t src = ((size_t)b * N_PIX + n0b + row) * 2 * C +
                             (part < 4 ? c0 + part * 8 : C + c0 + (part - 4) * 8);
                int dst = row * 72 + (part < 4 ? part * 8 : 32 + (part - 4) * 8);
                *(uint4*)&Xs[dst] = *(const uint4*)&xb[src];
            }
        }
        __syncthreads();

        bf16x8 ah[2], al[2];
        #pragma unroll
        for (int mf = 0; mf < 2; ++mf) {
            int base = (wo * 32 + mf * 16 + l15) * 72 + quad * 8;
            ah[mf] = *(const bf16x8*)&Ws[base];
            al[mf] = *(const bf16x8*)&Ws[base + 32];
        }
        #pragma unroll
        for (int nt = 0; nt < 8; ++nt) {
            int bbase = (wn * 128 + nt * 16 + l15) * 72 + quad * 8;
            bf16x8 bh = *(const bf16x8*)&Xs[bbase];
            bf16x8 bl = *(const bf16x8*)&Xs[bbase + 32];
            #pragma unroll
            for (int mf = 0; mf < 2; ++mf) {
                acc[mf][nt] = __builtin_amdgcn_mfma_f32_16x16x32_bf16(ah[mf], bh, acc[mf][nt], 0, 0, 0);
                acc[mf][nt] = __builtin_amdgcn_mfma_f32_16x16x32_bf16(ah[mf], bl, acc[mf][nt], 0, 0, 0);
                acc[mf][nt] = __builtin_amdgcn_mfma_f32_16x16x32_bf16(al[mf], bh, acc[mf][nt], 0, 0, 0);
            }
        }
    }

    float bv[2][4];
    #pragma unroll
    for (int mf = 0; mf < 2; ++mf)
        #pragma unroll
        for (int r = 0; r < 4; ++r)
            bv[mf][r] = bias[o0b + wo * 32 + mf * 16 + quad * 4 + r] * bscale;

    #pragma unroll
    for (int mf = 0; mf < 2; ++mf)
        #pragma unroll
        for (int nt = 0; nt < 8; ++nt) {
            int n = n0b + wn * 128 + nt * 16 + l15;
            float val[4];
            #pragma unroll
            for (int r = 0; r < 4; ++r) {
                float v = acc[mf][nt][r] + bv[mf][r];
                if (LRELU) v = (v > 0.f) ? v : 0.1f * v;
                val[r] = v;
            }
            int obase = o0b + wo * 32 + mf * 16 + quad * 4;
            if (MODE == 1) {
                __bf16* ob = (__bf16*)outp;
                #pragma unroll
                for (int r = 0; r < 4; ++r)
                    ob[((size_t)b * O + obase + r) * N_PIX + n] = (__bf16)val[r];
            } else if (MODE == 2) {
                __bf16* ob = (__bf16*)outp;
                bf16x4v hv, lv;
                #pragma unroll
                for (int r = 0; r < 4; ++r) {
                    hv[r] = (__bf16)val[r];
                    lv[r] = (__bf16)(val[r] - (float)hv[r]);
                }
                size_t rb = ((size_t)b * N_PIX + n) * 2 * O + obase;
                *(bf16x4v*)&ob[rb] = hv;
                *(bf16x4v*)&ob[rb + O] = lv;
            } else {  // MODE 4
                __bf16* ob = (__bf16*)outp;
                bf16x4v hv;
                #pragma unroll
                for (int r = 0; r < 4; ++r) hv[r] = (__bf16)val[r];
                *(bf16x4v*)&ob[((size_t)b * N_PIX + n) * O + obase] = hv;
            }
        }
}

// ---------------------------------------------------------------------------
// Attention kernel 1/2: E[b,q,k] = exp2(qk-dot), bf16, + per-row partial sums
// via atomicAdd into sums[b*N+q] (caller zeroes sums first).
// qt/kt row stride QSTR (packed [q|k] projection buffer).
// ---------------------------------------------------------------------------
template <int CQ>
__global__ __launch_bounds__(256)
void s_gemm(const __bf16* __restrict__ qt, const __bf16* __restrict__ kt,
            __bf16* __restrict__ S, float* __restrict__ sums, int QSTR) {
    constexpr int NKK = CQ / 32;
    __shared__ __bf16 Ss[128 * 136];
    int t = threadIdx.x;
    int lane = t & 63, w = t >> 6;
    int l15 = lane & 15, quad = lane >> 4;
    int k0 = blockIdx.x * 128, q0 = blockIdx.y * 128, b = blockIdx.z;

    bf16x8 kf[2][NKK], qf[8][NKK];
    #pragma unroll
    for (int mf = 0; mf < 2; ++mf)
        #pragma unroll
        for (int kk = 0; kk < NKK; ++kk)
            kf[mf][kk] = *(const bf16x8*)&kt[((size_t)b * N_PIX + k0 + w * 32 + mf * 16 + l15) * QSTR + kk * 32 + quad * 8];
    #pragma unroll
    for (int nt = 0; nt < 8; ++nt)
        #pragma unroll
        for (int kk = 0; kk < NKK; ++kk)
            qf[nt][kk] = *(const bf16x8*)&qt[((size_t)b * N_PIX + q0 + nt * 16 + l15) * QSTR + kk * 32 + quad * 8];

    f32x4 acc[2][8] = {};
    #pragma unroll
    for (int kk = 0; kk < NKK; ++kk)
        #pragma unroll
        for (int mf = 0; mf < 2; ++mf)
            #pragma unroll
            for (int nt = 0; nt < 8; ++nt)
                acc[mf][nt] = __builtin_amdgcn_mfma_f32_16x16x32_bf16(kf[mf][kk], qf[nt][kk], acc[mf][nt], 0, 0, 0);

    #pragma unroll
    for (int mf = 0; mf < 2; ++mf)
        #pragma unroll
        for (int nt = 0; nt < 8; ++nt) {
            bf16x4v pk;
            #pragma unroll
            for (int r = 0; r < 4; ++r) pk[r] = (__bf16)exp2f(acc[mf][nt][r]);
            *(bf16x4v*)&Ss[(nt * 16 + l15) * 136 + w * 32 + mf * 16 + quad * 4] = pk;
        }
    __syncthreads();
    // coalesced E write + per-row partial sum (this block's 128 keys)
    int ql = t >> 1, kh = (t & 1) * 64;
    size_t row = ((size_t)b * N_PIX + q0 + ql) * N_PIX + k0 + kh;
    float rs = 0.f;
    #pragma unroll
    for (int j = 0; j < 8; ++j) {
        bf16x8 v = *(const bf16x8*)&Ss[ql * 136 + kh + j * 8];
        #pragma unroll
        for (int e = 0; e < 8; ++e) rs += (float)v[e];
        *(bf16x8*)&S[row + j * 8] = v;
    }
    rs += __shfl_xor(rs, 1);  // combine the two k-halves (t, t^1: same row)
    if ((t & 1) == 0) atomicAdd(&sums[(size_t)b * N_PIX + q0 + ql], rs);
}

// ---------------------------------------------------------------------------
// Attention kernel 2/2: LDS-staged PV GEMM (M=128, grid 1024, XCD-pinned).
// O[b,q,c] = gamma / sums[q] * sum_k E[b,q,k] V[b,c,k] + residual.
// ---------------------------------------------------------------------------
template <int NT>
__global__ __launch_bounds__(256)
void pv_gemm5(const __bf16* __restrict__ E, const __bf16* __restrict__ vg,
              const float* __restrict__ sums, const __bf16* __restrict__ xin2,
              const float* __restrict__ gamma, float* __restrict__ out, int C) {
    constexpr int CCH = NT * 16;
    __shared__ __bf16 Psh[128 * 72];
    __shared__ __bf16 Vsh[CCH * 72];
    __shared__ float ilsh[128];
    int t = threadIdx.x;
    int lane = t & 63, w = t >> 6;
    int l15 = lane & 15, quad = lane >> 4;
    int bid = blockIdx.x;
    int pair = bid & 127, cblk = bid >> 7;
    int qi = pair >> 2, b = pair & 3;
    int q0 = qi * 128, c0 = cblk * CCH;
    const __bf16* Pb = E + ((size_t)b * N_PIX + q0) * N_PIX;
    const __bf16* Vb = vg + ((size_t)b * C + c0) * N_PIX;

    if (t < 128) ilsh[t] = 1.f / sums[(size_t)b * N_PIX + q0 + t];

    f32x4 acc[2][NT] = {};

    for (int k0 = 0; k0 < N_PIX; k0 += 64) {
        __syncthreads();
        #pragma unroll
        for (int i = 0; i < 4; ++i) {  // E tile: 128 q-rows x 64 k
            int e = t + i * 256;
            int row = e >> 3, seg = e & 7;
            *(uint4*)&Psh[row * 72 + seg * 8] = *(const uint4*)&Pb[(size_t)row * N_PIX + k0 + seg * 8];
        }
        for (int e = t; e < CCH * 8; e += 256) {  // V tile: CCH c-rows x 64 k
            int row = e >> 3, seg = e & 7;
            *(uint4*)&Vsh[row * 72 + seg * 8] = *(const uint4*)&Vb[(size_t)row * N_PIX + k0 + seg * 8];
        }
        __syncthreads();
        #pragma unroll
        for (int kk = 0; kk < 2; ++kk) {
            bf16x8 pa[2];
            #pragma unroll
            for (int mf = 0; mf < 2; ++mf)
                pa[mf] = *(const bf16x8*)&Psh[(w * 32 + mf * 16 + l15) * 72 + kk * 32 + quad * 8];
            #pragma unroll
            for (int nt = 0; nt < NT; ++nt) {
                bf16x8 vf = *(const bf16x8*)&Vsh[(nt * 16 + l15) * 72 + kk * 32 + quad * 8];
                #pragma unroll
                for (int mf = 0; mf < 2; ++mf)
                    acc[mf][nt] = __builtin_amdgcn_mfma_f32_16x16x32_bf16(pa[mf], vf, acc[mf][nt], 0, 0, 0);
            }
        }
    }

    float g = gamma[0];
    #pragma unroll
    for (int mf = 0; mf < 2; ++mf)
        #pragma unroll
        for (int r = 0; r < 4; ++r) {
            int ql = w * 32 + mf * 16 + quad * 4 + r;
            int q = q0 + ql;
            float gil = g * ilsh[ql];
            size_t xrb = ((size_t)b * N_PIX + q) * 2 * C;
            size_t orb = ((size_t)b * N_PIX + q) * C;
            #pragma unroll
            for (int nt = 0; nt < NT; ++nt) {
                int c = c0 + nt * 16 + l15;
                float xr = (float)xin2[xrb + c] + (float)xin2[xrb + C + c];
                out[orb + c] = gil * acc[mf][nt][r] + xr;
            }
        }
}

// ---------------------------------------------------------------------------
// L5: out[b,n] = lrelu(iv * dot(W5, h[b,n,:]) + b5).  h: (B,N,512) fp32.
// ---------------------------------------------------------------------------
__global__ __launch_bounds__(256)
void l5_kernel(const float* __restrict__ h, const float* __restrict__ W5,
               const float* __restrict__ b5, const float* __restrict__ sig,
               float* __restrict__ out) {
    int t = threadIdx.x;
    int lane = t & 63, w = t >> 6;
    int p = blockIdx.x * 4 + w;
    const float* row = h + (size_t)p * 512;
    float4 a0 = *(const float4*)&row[lane * 8];
    float4 a1 = *(const float4*)&row[lane * 8 + 4];
    float4 w0 = *(const float4*)&W5[lane * 8];
    float4 w1 = *(const float4*)&W5[lane * 8 + 4];
    float s = a0.x * w0.x + a0.y * w0.y + a0.z * w0.z + a0.w * w0.w +
              a1.x * w1.x + a1.y * w1.y + a1.z * w1.z + a1.w * w1.w;
    #pragma unroll
    for (int off = 1; off < 64; off <<= 1) s += __shfl_xor(s, off);
    if (lane == 0) {
        float v = sig[0] * s + b5[0];
        out[p] = (v > 0.f) ? v : 0.1f * v;
    }
}

// ---------------------------------------------------------------------------
// Launcher
// ---------------------------------------------------------------------------
extern "C" void kernel_launch(void* const* d_in, const int* in_sizes, int n_in,
                              void* d_out, int out_size, void* d_ws, size_t ws_size,
                              hipStream_t stream) {
    const float* x   = (const float*)d_in[0];
    const float* W1  = (const float*)d_in[1];
    const float* b1  = (const float*)d_in[2];
    const float* u1  = (const float*)d_in[3];
    const float* W2  = (const float*)d_in[4];
    const float* b2  = (const float*)d_in[5];
    const float* u2  = (const float*)d_in[6];
    const float* W3  = (const float*)d_in[7];
    const float* b3  = (const float*)d_in[8];
    const float* u3  = (const float*)d_in[9];
    const float* W4  = (const float*)d_in[10];
    const float* b4  = (const float*)d_in[11];
    const float* u4  = (const float*)d_in[12];
    const float* W5  = (const float*)d_in[13];
    const float* b5  = (const float*)d_in[14];
    const float* u5  = (const float*)d_in[15];
    const float* a1_qW = (const float*)d_in[16];
    const float* a1_qb = (const float*)d_in[17];
    const float* a1_kW = (const float*)d_in[18];
    const float* a1_kb = (const float*)d_in[19];
    const float* a1_vW = (const float*)d_in[20];
    const float* a1_vb = (const float*)d_in[21];
    const float* a1_g  = (const float*)d_in[22];
    const float* a2_qW = (const float*)d_in[23];
    const float* a2_qb = (const float*)d_in[24];
    const float* a2_kW = (const float*)d_in[25];
    const float* a2_kb = (const float*)d_in[26];
    const float* a2_vW = (const float*)d_in[27];
    const float* a2_vb = (const float*)d_in[28];
    const float* a2_g  = (const float*)d_in[29];

    float* ws = (float*)d_ws;
    const size_t NF = (size_t)BATCH * N_PIX;  // 16384
    float* sig    = ws;                       // 16
    float* h1     = ws + 16;                  // NF*64 fl (reused as sums)
    float* slabC  = h1 + NF * 64;             // NF*512 fl
    float* slabS1 = slabC + NF * 512;         // NF*256 fl
    float* slabS2 = slabS1 + NF * 256;        // NF*512 fl
    float* qtf    = slabS2 + NF * 512;        // NF*32 fl
    float* ktf    = qtf + NF * 32;            // NF*32 fl
    float* wspf   = ktf + NF * 32;            // ~0.6M fl
    float* bbf    = wspf + 592000;            // 192 fl bias concat
    float* Sf     = wspf + 600000;            // E: NF*4096 bf16

    __bf16* h1t = (__bf16*)slabS1;            // (B,N,128)
    __bf16* h2t = (__bf16*)slabS2;            // (B,N,256)
    __bf16* h3t = (__bf16*)slabS1;            // (B,N,512)
    __bf16* h5t = (__bf16*)slabS2;            // (B,N,1024)
    float*  h4t = slabC;                      // (B,N,256) fp32
    __bf16* vb1 = (__bf16*)(slabC + NF * 256);// (B,256,N)
    float*  h6t = slabC;                      // (B,N,512) fp32
    __bf16* vb2 = (__bf16*)slabS1;            // (B,512,N)
    __bf16* qkt = (__bf16*)qtf;               // (B,N,2CQ) packed [q|k]
    __bf16* wsp = (__bf16*)wspf;
    __bf16* Sbuf = (__bf16*)Sf;               // (B,4096,4096) bf16
    float*  sums = h1;                        // B*N floats (h1 dead after tsplit)

    __bf16* wsL2  = wsp;            // 128*128
    __bf16* wsL3  = wsL2 + 16384;   // 256*256
    __bf16* wsL4  = wsL3 + 65536;   // 512*512
    __bf16* wsA1q = wsL4 + 262144;  // 32*512   [combined with wsA1k: (64,512)]
    __bf16* wsA1k = wsA1q + 16384;
    __bf16* wsA1v = wsA1k + 16384;  // 256*512
    __bf16* wsA2q = wsA1v + 131072; // 64*1024  [combined with wsA2k: (128,1024)]
    __bf16* wsA2k = wsA2q + 65536;
    __bf16* wsA2v = wsA2k + 65536;  // 512*1024

    dim3 blk(256);

    SigP sp;
    sp.W[0] = W1; sp.u[0] = u1; sp.O[0] = 64;  sp.C[0] = 6;
    sp.W[1] = W2; sp.u[1] = u2; sp.O[1] = 128; sp.C[1] = 64;
    sp.W[2] = W3; sp.u[2] = u3; sp.O[2] = 256; sp.C[2] = 128;
    sp.W[3] = W4; sp.u[3] = u4; sp.O[3] = 512; sp.C[3] = 256;
    sp.W[4] = W5; sp.u[4] = u5; sp.O[4] = 1;   sp.C[4] = 512;
    sigma_all<<<dim3(5), dim3(1024), 0, stream>>>(sp, sig);

    concat_bias<<<1, blk, 0, stream>>>(a1_qb, a1_kb, a2_qb, a2_kb, bbf);

    wsplit_kernel<<<128, blk, 0, stream>>>(W2, sig + 1, 1.f, 64, wsL2);
    wsplit_kernel<<<256, blk, 0, stream>>>(W3, sig + 2, 1.f, 128, wsL3);
    wsplit_kernel<<<512, blk, 0, stream>>>(W4, sig + 3, 1.f, 256, wsL4);
    wsplit_kernel<<<32,  blk, 0, stream>>>(a1_qW, nullptr, LOG2E, 256, wsA1q);
    wsplit_kernel<<<32,  blk, 0, stream>>>(a1_kW, nullptr, 1.f, 256, wsA1k);
    wsplit_kernel<<<256, blk, 0, stream>>>(a1_vW, nullptr, 1.f, 256, wsA1v);
    wsplit_kernel<<<64,  blk, 0, stream>>>(a2_qW, nullptr, LOG2E, 512, wsA2q);
    wsplit_kernel<<<64,  blk, 0, stream>>>(a2_kW, nullptr, 1.f, 512, wsA2k);
    wsplit_kernel<<<512, blk, 0, stream>>>(a2_vW, nullptr, 1.f, 512, wsA2v);

    // L1 (fp32) + transpose/split
    conv_f32_kernel<<<dim3(64, 1, 4), blk, 0, stream>>>(x, W1, b1, sig + 0, h1, 6, 64, 1);
    tsplit64_kernel<<<dim3(64, 4), blk, 0, stream>>>(h1, h1t);

    // L2, L3 (split-MFMA)
    mfma_conv<4, 1, 2, 0, 1><<<dim3(32, 1, 4), blk, 0, stream>>>(h1t, wsL2, b2, 1.f, h2t, 64, 128);
    mfma_conv<4, 1, 2, 0, 1><<<dim3(32, 2, 4), blk, 0, stream>>>(h2t, wsL3, b3, 1.f, h3t, 128, 256);

    // attention 1 (C=256, Cq=32): fused q|k projection -> (B,N,64)
    mfma_conv<2, 2, 4, 0, 0><<<dim3(16, 1, 4), blk, 0, stream>>>(h3t, wsA1q, bbf, 1.f, qkt, 256, 64);
    mfma_conv<4, 1, 1, 0, 0><<<dim3(32, 2, 4), blk, 0, stream>>>(h3t, wsA1v, a1_vb, 1.f, vb1, 256, 256);
    hipMemsetAsync(sums, 0, NF * sizeof(float), stream);
    s_gemm<32><<<dim3(32, 32, 4), blk, 0, stream>>>(qkt, qkt + 32, Sbuf, sums, 64);
    pv_gemm5<2><<<dim3(1024), blk, 0, stream>>>(Sbuf, vb1, sums, h3t, a1_g, h4t, 256);

    // L4 (fp32-transposed input)
    mfma_conv<4, 1, 2, 1, 1><<<dim3(32, 4, 4), blk, 0, stream>>>(h4t, wsL4, b4, 1.f, h5t, 256, 512);

    // attention 2 (C=512, Cq=64): fused q|k projection -> (B,N,128)
    mfma_conv<2, 2, 4, 0, 0><<<dim3(16, 2, 4), blk, 0, stream>>>(h5t, wsA2q, bbf + 64, 1.f, qkt, 512, 128);
    mfma_conv<4, 1, 1, 0, 0><<<dim3(32, 4, 4), blk, 0, stream>>>(h5t, wsA2v, a2_vb, 1.f, vb2, 512, 512);
    hipMemsetAsync(sums, 0, NF * sizeof(float), stream);
    s_gemm<64><<<dim3(32, 32, 4), blk, 0, stream>>>(qkt, qkt + 64, Sbuf, sums, 128);
    pv_gemm5<4><<<dim3(1024), blk, 0, stream>>>(Sbuf, vb2, sums, h5t, a2_g, h6t, 512);

    // L5
    l5_kernel<<<4096, blk, 0, stream>>>(h6t, W5, b5, sig + 4, (float*)d_out);
}

// Round 16
// 804.542 us; speedup vs baseline: 1.2169x; 1.0147x over previous
//
#include <hip/hip_runtime.h>
#include <math.h>

#define N_PIX 4096  // H*W = 64*64
#define BATCH 4
#define LOG2E 1.4426950408889634f

typedef __bf16 bf16x8 __attribute__((ext_vector_type(8)));
typedef __bf16 bf16x4v __attribute__((ext_vector_type(4)));
typedef float f32x4 __attribute__((ext_vector_type(4)));

// ---------------------------------------------------------------------------
// Fused spectral norms: one block per layer, 1024 threads (16 waves).
// ---------------------------------------------------------------------------
struct SigP {
    const float* W[5];
    const float* u[5];
    int O[5];
    int C[5];
};

__global__ __launch_bounds__(1024)
void sigma_all(SigP p, float* __restrict__ out_inv) {
    __shared__ float ush[512];
    __shared__ float vsh[512];
    __shared__ float vpart[16 * 512];
    __shared__ float redl[1024];
    int L = blockIdx.x;
    const float* W = p.W[L];
    const float* u = p.u[L];
    int O = p.O[L], C = p.C[L];
    int t = threadIdx.x;
    int w = t >> 6, lane = t & 63;

    for (int i = t; i < O; i += 1024) ush[i] = u[i];
    __syncthreads();

    int o_beg = (O * w) >> 4, o_end = (O * (w + 1)) >> 4;
    for (int c = lane; c < C; c += 64) {
        float a = 0.f;
        for (int o = o_beg; o < o_end; ++o) a += W[(size_t)o * C + c] * ush[o];
        vpart[w * 512 + c] = a;
    }
    __syncthreads();

    float nn = 0.f;
    for (int c = t; c < C; c += 1024) {
        float s = 0.f;
        #pragma unroll
        for (int w2 = 0; w2 < 16; ++w2) s += vpart[w2 * 512 + c];
        vsh[c] = s;
        nn += s * s;
    }
    redl[t] = nn;
    __syncthreads();
    for (int s = 512; s > 0; s >>= 1) {
        if (t < s) redl[t] += redl[t + s];
        __syncthreads();
    }
    float nrm2 = redl[0];
    __syncthreads();
    float rinv = 1.f / (sqrtf(nrm2) + 1e-12f);

    float sq = 0.f;
    for (int o = w; o < O; o += 16) {
        float a = 0.f;
        for (int c = lane; c < C; c += 64) a += W[(size_t)o * C + c] * vsh[c];
        #pragma unroll
        for (int off = 1; off < 64; off <<= 1) a += __shfl_xor(a, off);
        if (lane == 0) sq += a * a;
    }
    if (lane == 0) redl[w] = sq;
    __syncthreads();
    if (t == 0) {
        float ns2raw = 0.f;
        #pragma unroll
        for (int i = 0; i < 16; ++i) ns2raw += redl[i];
        float ns2 = rinv * rinv * ns2raw;
        float sg = ns2 / (sqrtf(ns2) + 1e-12f);
        out_inv[L] = 1.f / sg;
    }
}

// ---------------------------------------------------------------------------
// Weight split: (O,C) fp32 * iv * scale -> (O, 2C) bf16  [hi | lo].
// ---------------------------------------------------------------------------
__global__ __launch_bounds__(256)
void wsplit_kernel(const float* __restrict__ W, const float* __restrict__ iv,
                   float scale, int C, __bf16* __restrict__ out) {
    int o = blockIdx.x;
    float s = (iv ? iv[0] : 1.f) * scale;
    for (int c = threadIdx.x; c < C; c += 256) {
        float wv = W[(size_t)o * C + c] * s;
        __bf16 hi = (__bf16)wv;
        float lo = wv - (float)hi;
        out[(size_t)o * 2 * C + c] = hi;
        out[(size_t)o * 2 * C + C + c] = (__bf16)lo;
    }
}

// ---------------------------------------------------------------------------
// Concat + prescale attention projection biases.
// ---------------------------------------------------------------------------
__global__ __launch_bounds__(256)
void concat_bias(const float* __restrict__ qb1, const float* __restrict__ kb1,
                 const float* __restrict__ qb2, const float* __restrict__ kb2,
                 float* __restrict__ bb) {
    int t = threadIdx.x;
    if (t < 32) bb[t] = qb1[t] * LOG2E;
    else if (t < 64) bb[t] = kb1[t - 32];
    else if (t < 128) bb[t] = qb2[t - 64] * LOG2E;
    else if (t < 192) bb[t] = kb2[t - 128];
}

// ---------------------------------------------------------------------------
// L1 only: fp32 VALU conv (C=6). x (B,C,N) -> out (B,O,N) fp32.
// ---------------------------------------------------------------------------
__global__ __launch_bounds__(256)
void conv_f32_kernel(const float* __restrict__ x, const float* __restrict__ W,
                     const float* __restrict__ bias, const float* __restrict__ sig,
                     float* __restrict__ out, int C, int O, int lrelu) {
    __shared__ float Ws[16][68];
    __shared__ float Xs[16][68];
    int t = threadIdx.x;
    int tx = t & 15, ty = t >> 4;
    int b = blockIdx.z;
    int n0 = blockIdx.x * 64, o0 = blockIdx.y * 64;
    float acc[4][4] = {};
    const float* xb = x + (size_t)b * C * N_PIX;
    for (int c0 = 0; c0 < C; c0 += 16) {
        #pragma unroll
        for (int i = 0; i < 4; ++i) {
            int e = t + i * 256;
            int o = e >> 4, c = e & 15;
            float wv = 0.f;
            if (o0 + o < O && c0 + c < C) wv = W[(size_t)(o0 + o) * C + c0 + c];
            Ws[c][o] = wv;
        }
        #pragma unroll
        for (int i = 0; i < 4; ++i) {
            int e = t + i * 256;
            int c = e >> 6, n = e & 63;
            float xv = 0.f;
            if (c0 + c < C) xv = xb[(size_t)(c0 + c) * N_PIX + n0 + n];
            Xs[c][n] = xv;
        }
        __syncthreads();
        #pragma unroll
        for (int cc = 0; cc < 16; ++cc) {
            float4 wv = *(const float4*)&Ws[cc][ty * 4];
            float4 xv = *(const float4*)&Xs[cc][tx * 4];
            float wa[4] = {wv.x, wv.y, wv.z, wv.w};
            float xa[4] = {xv.x, xv.y, xv.z, xv.w};
            #pragma unroll
            for (int i = 0; i < 4; ++i)
                #pragma unroll
                for (int j = 0; j < 4; ++j)
                    acc[i][j] += wa[i] * xa[j];
        }
        __syncthreads();
    }
    float ivv = sig ? sig[0] : 1.f;
    for (int i = 0; i < 4; ++i) {
        int o = o0 + ty * 4 + i;
        if (o >= O) break;
        float bv = bias[o];
        float vres[4];
        #pragma unroll
        for (int j = 0; j < 4; ++j) {
            float v = acc[i][j] * ivv + bv;
            if (lrelu) v = (v > 0.f) ? v : 0.1f * v;
            vres[j] = v;
        }
        *(float4*)&out[((size_t)b * O + o) * N_PIX + n0 + tx * 4] =
            make_float4(vres[0], vres[1], vres[2], vres[3]);
    }
}

// ---------------------------------------------------------------------------
// Transpose+split: (B,64,N) fp32 -> (B,N,128) bf16 [hi(64)|lo(64)].
// ---------------------------------------------------------------------------
__global__ __launch_bounds__(256)
void tsplit64_kernel(const float* __restrict__ in, __bf16* __restrict__ out) {
    __shared__ float tile[64 * 65];
    int t = threadIdx.x;
    int n0 = blockIdx.x * 64, b = blockIdx.y;
    for (int e = t; e < 64 * 64; e += 256) {
        int c = e >> 6, n = e & 63;
        tile[n * 65 + c] = in[((size_t)b * 64 + c) * N_PIX + n0 + n];
    }
    __syncthreads();
    for (int e = t; e < 64 * 64; e += 256) {
        int n = e >> 6, c = e & 63;
        float v = tile[n * 65 + c];
        __bf16 hi = (__bf16)v;
        size_t base = ((size_t)b * N_PIX + n0 + n) * 128;
        out[base + c] = hi;
        out[base + 64 + c] = (__bf16)(v - (float)hi);
    }
}

// ---------------------------------------------------------------------------
// Split-bf16 MFMA 1x1 conv. MF = m-frags per wave (1 or 2).
// Block o-tile = WO*16*MF; MF=1 doubles grid for latency-bound small convs.
// ---------------------------------------------------------------------------
template <int WO, int WN, int MF, int MODE, int IN_F32, int LRELU>
__global__ __launch_bounds__(256)
void mfma_conv(const void* __restrict__ xt, const __bf16* __restrict__ wsp,
               const float* __restrict__ bias, float bscale,
               void* __restrict__ outp, int C, int O) {
    constexpr int NT_BLK = WN * 128;
    constexpr int OT_BLK = WO * 16 * MF;
    __shared__ __bf16 Ws[OT_BLK * 72];
    __shared__ __bf16 Xs[NT_BLK * 72];
    int t = threadIdx.x;
    int lane = t & 63, w = t >> 6;
    int l15 = lane & 15, quad = lane >> 4;
    int wo = w / WN, wn = w % WN;
    int b = blockIdx.z;
    int n0b = blockIdx.x * NT_BLK, o0b = blockIdx.y * OT_BLK;

    f32x4 acc[MF][8] = {};

    for (int c0 = 0; c0 < C; c0 += 32) {
        __syncthreads();
        for (int e = t; e < OT_BLK * 8; e += 256) {
            int row = e >> 3, part = e & 7;
            size_t src = (size_t)(o0b + row) * 2 * C +
                         (part < 4 ? c0 + part * 8 : C + c0 + (part - 4) * 8);
            int dst = row * 72 + (part < 4 ? part * 8 : 32 + (part - 4) * 8);
            *(uint4*)&Ws[dst] = *(const uint4*)&wsp[src];
        }
        if (IN_F32) {
            const float* xf = (const float*)xt;
            for (int e = t; e < NT_BLK * 8; e += 256) {
                int row = e >> 3, part = e & 7;
                float4 v = *(const float4*)&xf[((size_t)b * N_PIX + n0b + row) * C + c0 + part * 4];
                bf16x4v hi, lo;
                float va[4] = {v.x, v.y, v.z, v.w};
                #pragma unroll
                for (int j = 0; j < 4; ++j) {
                    hi[j] = (__bf16)va[j];
                    lo[j] = (__bf16)(va[j] - (float)hi[j]);
                }
                *(bf16x4v*)&Xs[row * 72 + part * 4] = hi;
                *(bf16x4v*)&Xs[row * 72 + 32 + part * 4] = lo;
            }
        } else {
            const __bf16* xb = (const __bf16*)xt;
            for (int e = t; e < NT_BLK * 8; e += 256) {
                int row = e >> 3, part = e & 7;
                size_t src = ((size_t)b * N_PIX + n0b + row) * 2 * C +
                             (part < 4 ? c0 + part * 8 : C + c0 + (part - 4) * 8);
                int dst = row * 72 + (part < 4 ? part * 8 : 32 + (part - 4) * 8);
                *(uint4*)&Xs[dst] = *(const uint4*)&xb[src];
            }
        }
        __syncthreads();

        bf16x8 ah[MF], al[MF];
        #pragma unroll
        for (int mf = 0; mf < MF; ++mf) {
            int base = (wo * 16 * MF + mf * 16 + l15) * 72 + quad * 8;
            ah[mf] = *(const bf16x8*)&Ws[base];
            al[mf] = *(const bf16x8*)&Ws[base + 32];
        }
        #pragma unroll
        for (int nt = 0; nt < 8; ++nt) {
            int bbase = (wn * 128 + nt * 16 + l15) * 72 + quad * 8;
            bf16x8 bh = *(const bf16x8*)&Xs[bbase];
            bf16x8 bl = *(const bf16x8*)&Xs[bbase + 32];
            #pragma unroll
            for (int mf = 0; mf < MF; ++mf) {
                acc[mf][nt] = __builtin_amdgcn_mfma_f32_16x16x32_bf16(ah[mf], bh, acc[mf][nt], 0, 0, 0);
                acc[mf][nt] = __builtin_amdgcn_mfma_f32_16x16x32_bf16(ah[mf], bl, acc[mf][nt], 0, 0, 0);
                acc[mf][nt] = __builtin_amdgcn_mfma_f32_16x16x32_bf16(al[mf], bh, acc[mf][nt], 0, 0, 0);
            }
        }
    }

    float bv[MF][4];
    #pragma unroll
    for (int mf = 0; mf < MF; ++mf)
        #pragma unroll
        for (int r = 0; r < 4; ++r)
            bv[mf][r] = bias[o0b + wo * 16 * MF + mf * 16 + quad * 4 + r] * bscale;

    #pragma unroll
    for (int mf = 0; mf < MF; ++mf)
        #pragma unroll
        for (int nt = 0; nt < 8; ++nt) {
            int n = n0b + wn * 128 + nt * 16 + l15;
            float val[4];
            #pragma unroll
            for (int r = 0; r < 4; ++r) {
                float v = acc[mf][nt][r] + bv[mf][r];
                if (LRELU) v = (v > 0.f) ? v : 0.1f * v;
                val[r] = v;
            }
            int obase = o0b + wo * 16 * MF + mf * 16 + quad * 4;
            if (MODE == 1) {
                __bf16* ob = (__bf16*)outp;
                #pragma unroll
                for (int r = 0; r < 4; ++r)
                    ob[((size_t)b * O + obase + r) * N_PIX + n] = (__bf16)val[r];
            } else if (MODE == 2) {
                __bf16* ob = (__bf16*)outp;
                bf16x4v hv, lv;
                #pragma unroll
                for (int r = 0; r < 4; ++r) {
                    hv[r] = (__bf16)val[r];
                    lv[r] = (__bf16)(val[r] - (float)hv[r]);
                }
                size_t rb = ((size_t)b * N_PIX + n) * 2 * O + obase;
                *(bf16x4v*)&ob[rb] = hv;
                *(bf16x4v*)&ob[rb + O] = lv;
            } else {  // MODE 4
                __bf16* ob = (__bf16*)outp;
                bf16x4v hv;
                #pragma unroll
                for (int r = 0; r < 4; ++r) hv[r] = (__bf16)val[r];
                *(bf16x4v*)&ob[((size_t)b * N_PIX + n) * O + obase] = hv;
            }
        }
}

// ---------------------------------------------------------------------------
// Attention kernel 1/2: E = exp2(qk-dot), bf16, + per-row atomic partial sums.
// ---------------------------------------------------------------------------
template <int CQ>
__global__ __launch_bounds__(256)
void s_gemm(const __bf16* __restrict__ qt, const __bf16* __restrict__ kt,
            __bf16* __restrict__ S, float* __restrict__ sums, int QSTR) {
    constexpr int NKK = CQ / 32;
    __shared__ __bf16 Ss[128 * 136];
    int t = threadIdx.x;
    int lane = t & 63, w = t >> 6;
    int l15 = lane & 15, quad = lane >> 4;
    int k0 = blockIdx.x * 128, q0 = blockIdx.y * 128, b = blockIdx.z;

    bf16x8 kf[2][NKK], qf[8][NKK];
    #pragma unroll
    for (int mf = 0; mf < 2; ++mf)
        #pragma unroll
        for (int kk = 0; kk < NKK; ++kk)
            kf[mf][kk] = *(const bf16x8*)&kt[((size_t)b * N_PIX + k0 + w * 32 + mf * 16 + l15) * QSTR + kk * 32 + quad * 8];
    #pragma unroll
    for (int nt = 0; nt < 8; ++nt)
        #pragma unroll
        for (int kk = 0; kk < NKK; ++kk)
            qf[nt][kk] = *(const bf16x8*)&qt[((size_t)b * N_PIX + q0 + nt * 16 + l15) * QSTR + kk * 32 + quad * 8];

    f32x4 acc[2][8] = {};
    #pragma unroll
    for (int kk = 0; kk < NKK; ++kk)
        #pragma unroll
        for (int mf = 0; mf < 2; ++mf)
            #pragma unroll
            for (int nt = 0; nt < 8; ++nt)
                acc[mf][nt] = __builtin_amdgcn_mfma_f32_16x16x32_bf16(kf[mf][kk], qf[nt][kk], acc[mf][nt], 0, 0, 0);

    #pragma unroll
    for (int mf = 0; mf < 2; ++mf)
        #pragma unroll
        for (int nt = 0; nt < 8; ++nt) {
            bf16x4v pk;
            #pragma unroll
            for (int r = 0; r < 4; ++r) pk[r] = (__bf16)exp2f(acc[mf][nt][r]);
            *(bf16x4v*)&Ss[(nt * 16 + l15) * 136 + w * 32 + mf * 16 + quad * 4] = pk;
        }
    __syncthreads();
    int ql = t >> 1, kh = (t & 1) * 64;
    size_t row = ((size_t)b * N_PIX + q0 + ql) * N_PIX + k0 + kh;
    float rs = 0.f;
    #pragma unroll
    for (int j = 0; j < 8; ++j) {
        bf16x8 v = *(const bf16x8*)&Ss[ql * 136 + kh + j * 8];
        #pragma unroll
        for (int e = 0; e < 8; ++e) rs += (float)v[e];
        *(bf16x8*)&S[row + j * 8] = v;
    }
    rs += __shfl_xor(rs, 1);
    if ((t & 1) == 0) atomicAdd(&sums[(size_t)b * N_PIX + q0 + ql], rs);
}

// ---------------------------------------------------------------------------
// Attention kernel 2/2: LDS-staged PV GEMM (M=128, grid 1024, XCD-pinned).
// ---------------------------------------------------------------------------
template <int NT>
__global__ __launch_bounds__(256)
void pv_gemm5(const __bf16* __restrict__ E, const __bf16* __restrict__ vg,
              const float* __restrict__ sums, const __bf16* __restrict__ xin2,
              const float* __restrict__ gamma, float* __restrict__ out, int C) {
    constexpr int CCH = NT * 16;
    __shared__ __bf16 Psh[128 * 72];
    __shared__ __bf16 Vsh[CCH * 72];
    __shared__ float ilsh[128];
    int t = threadIdx.x;
    int lane = t & 63, w = t >> 6;
    int l15 = lane & 15, quad = lane >> 4;
    int bid = blockIdx.x;
    int pair = bid & 127, cblk = bid >> 7;
    int qi = pair >> 2, b = pair & 3;
    int q0 = qi * 128, c0 = cblk * CCH;
    const __bf16* Pb = E + ((size_t)b * N_PIX + q0) * N_PIX;
    const __bf16* Vb = vg + ((size_t)b * C + c0) * N_PIX;

    if (t < 128) ilsh[t] = 1.f / sums[(size_t)b * N_PIX + q0 + t];

    f32x4 acc[2][NT] = {};

    for (int k0 = 0; k0 < N_PIX; k0 += 64) {
        __syncthreads();
        #pragma unroll
        for (int i = 0; i < 4; ++i) {
            int e = t + i * 256;
            int row = e >> 3, seg = e & 7;
            *(uint4*)&Psh[row * 72 + seg * 8] = *(const uint4*)&Pb[(size_t)row * N_PIX + k0 + seg * 8];
        }
        for (int e = t; e < CCH * 8; e += 256) {
            int row = e >> 3, seg = e & 7;
            *(uint4*)&Vsh[row * 72 + seg * 8] = *(const uint4*)&Vb[(size_t)row * N_PIX + k0 + seg * 8];
        }
        __syncthreads();
        #pragma unroll
        for (int kk = 0; kk < 2; ++kk) {
            bf16x8 pa[2];
            #pragma unroll
            for (int mf = 0; mf < 2; ++mf)
                pa[mf] = *(const bf16x8*)&Psh[(w * 32 + mf * 16 + l15) * 72 + kk * 32 + quad * 8];
            #pragma unroll
            for (int nt = 0; nt < NT; ++nt) {
                bf16x8 vf = *(const bf16x8*)&Vsh[(nt * 16 + l15) * 72 + kk * 32 + quad * 8];
                #pragma unroll
                for (int mf = 0; mf < 2; ++mf)
                    acc[mf][nt] = __builtin_amdgcn_mfma_f32_16x16x32_bf16(pa[mf], vf, acc[mf][nt], 0, 0, 0);
            }
        }
    }

    float g = gamma[0];
    #pragma unroll
    for (int mf = 0; mf < 2; ++mf)
        #pragma unroll
        for (int r = 0; r < 4; ++r) {
            int ql = w * 32 + mf * 16 + quad * 4 + r;
            int q = q0 + ql;
            float gil = g * ilsh[ql];
            size_t xrb = ((size_t)b * N_PIX + q) * 2 * C;
            size_t orb = ((size_t)b * N_PIX + q) * C;
            #pragma unroll
            for (int nt = 0; nt < NT; ++nt) {
                int c = c0 + nt * 16 + l15;
                float xr = (float)xin2[xrb + c] + (float)xin2[xrb + C + c];
                out[orb + c] = gil * acc[mf][nt][r] + xr;
            }
        }
}

// ---------------------------------------------------------------------------
// L5: out[b,n] = lrelu(iv * dot(W5, h[b,n,:]) + b5).  h: (B,N,512) fp32.
// ---------------------------------------------------------------------------
__global__ __launch_bounds__(256)
void l5_kernel(const float* __restrict__ h, const float* __restrict__ W5,
               const float* __restrict__ b5, const float* __restrict__ sig,
               float* __restrict__ out) {
    int t = threadIdx.x;
    int lane = t & 63, w = t >> 6;
    int p = blockIdx.x * 4 + w;
    const float* row = h + (size_t)p * 512;
    float4 a0 = *(const float4*)&row[lane * 8];
    float4 a1 = *(const float4*)&row[lane * 8 + 4];
    float4 w0 = *(const float4*)&W5[lane * 8];
    float4 w1 = *(const float4*)&W5[lane * 8 + 4];
    float s = a0.x * w0.x + a0.y * w0.y + a0.z * w0.z + a0.w * w0.w +
              a1.x * w1.x + a1.y * w1.y + a1.z * w1.z + a1.w * w1.w;
    #pragma unroll
    for (int off = 1; off < 64; off <<= 1) s += __shfl_xor(s, off);
    if (lane == 0) {
        float v = sig[0] * s + b5[0];
        out[p] = (v > 0.f) ? v : 0.1f * v;
    }
}

// ---------------------------------------------------------------------------
// Launcher
// ---------------------------------------------------------------------------
extern "C" void kernel_launch(void* const* d_in, const int* in_sizes, int n_in,
                              void* d_out, int out_size, void* d_ws, size_t ws_size,
                              hipStream_t stream) {
    const float* x   = (const float*)d_in[0];
    const float* W1  = (const float*)d_in[1];
    const float* b1  = (const float*)d_in[2];
    const float* u1  = (const float*)d_in[3];
    const float* W2  = (const float*)d_in[4];
    const float* b2  = (const float*)d_in[5];
    const float* u2  = (const float*)d_in[6];
    const float* W3  = (const float*)d_in[7];
    const float* b3  = (const float*)d_in[8];
    const float* u3  = (const float*)d_in[9];
    const float* W4  = (const float*)d_in[10];
    const float* b4  = (const float*)d_in[11];
    const float* u4  = (const float*)d_in[12];
    const float* W5  = (const float*)d_in[13];
    const float* b5  = (const float*)d_in[14];
    const float* u5  = (const float*)d_in[15];
    const float* a1_qW = (const float*)d_in[16];
    const float* a1_qb = (const float*)d_in[17];
    const float* a1_kW = (const float*)d_in[18];
    const float* a1_kb = (const float*)d_in[19];
    const float* a1_vW = (const float*)d_in[20];
    const float* a1_vb = (const float*)d_in[21];
    const float* a1_g  = (const float*)d_in[22];
    const float* a2_qW = (const float*)d_in[23];
    const float* a2_qb = (const float*)d_in[24];
    const float* a2_kW = (const float*)d_in[25];
    const float* a2_kb = (const float*)d_in[26];
    const float* a2_vW = (const float*)d_in[27];
    const float* a2_vb = (const float*)d_in[28];
    const float* a2_g  = (const float*)d_in[29];

    float* ws = (float*)d_ws;
    const size_t NF = (size_t)BATCH * N_PIX;  // 16384
    float* sig    = ws;                       // 16
    float* h1     = ws + 16;                  // NF*64 fl (reused as sums)
    float* slabC  = h1 + NF * 64;             // NF*512 fl
    float* slabS1 = slabC + NF * 512;         // NF*256 fl
    float* slabS2 = slabS1 + NF * 256;        // NF*512 fl
    float* qtf    = slabS2 + NF * 512;        // NF*32 fl
    float* ktf    = qtf + NF * 32;            // NF*32 fl
    float* wspf   = ktf + NF * 32;            // ~0.6M fl
    float* bbf    = wspf + 592000;            // 192 fl bias concat
    float* Sf     = wspf + 600000;            // E: NF*4096 bf16

    __bf16* h1t = (__bf16*)slabS1;            // (B,N,128)
    __bf16* h2t = (__bf16*)slabS2;            // (B,N,256)
    __bf16* h3t = (__bf16*)slabS1;            // (B,N,512)
    __bf16* h5t = (__bf16*)slabS2;            // (B,N,1024)
    float*  h4t = slabC;                      // (B,N,256) fp32
    __bf16* vb1 = (__bf16*)(slabC + NF * 256);// (B,256,N)
    float*  h6t = slabC;                      // (B,N,512) fp32
    __bf16* vb2 = (__bf16*)slabS1;            // (B,512,N)
    __bf16* qkt = (__bf16*)qtf;               // (B,N,2CQ) packed [q|k]
    __bf16* wsp = (__bf16*)wspf;
    __bf16* Sbuf = (__bf16*)Sf;               // (B,4096,4096) bf16
    float*  sums = h1;                        // B*N floats (h1 dead after tsplit)

    __bf16* wsL2  = wsp;            // 128*128
    __bf16* wsL3  = wsL2 + 16384;   // 256*256
    __bf16* wsL4  = wsL3 + 65536;   // 512*512
    __bf16* wsA1q = wsL4 + 262144;  // 32*512   [combined with wsA1k: (64,512)]
    __bf16* wsA1k = wsA1q + 16384;
    __bf16* wsA1v = wsA1k + 16384;  // 256*512
    __bf16* wsA2q = wsA1v + 131072; // 64*1024  [combined with wsA2k: (128,1024)]
    __bf16* wsA2k = wsA2q + 65536;
    __bf16* wsA2v = wsA2k + 65536;  // 512*1024

    dim3 blk(256);

    SigP sp;
    sp.W[0] = W1; sp.u[0] = u1; sp.O[0] = 64;  sp.C[0] = 6;
    sp.W[1] = W2; sp.u[1] = u2; sp.O[1] = 128; sp.C[1] = 64;
    sp.W[2] = W3; sp.u[2] = u3; sp.O[2] = 256; sp.C[2] = 128;
    sp.W[3] = W4; sp.u[3] = u4; sp.O[3] = 512; sp.C[3] = 256;
    sp.W[4] = W5; sp.u[4] = u5; sp.O[4] = 1;   sp.C[4] = 512;
    sigma_all<<<dim3(5), dim3(1024), 0, stream>>>(sp, sig);

    concat_bias<<<1, blk, 0, stream>>>(a1_qb, a1_kb, a2_qb, a2_kb, bbf);

    wsplit_kernel<<<128, blk, 0, stream>>>(W2, sig + 1, 1.f, 64, wsL2);
    wsplit_kernel<<<256, blk, 0, stream>>>(W3, sig + 2, 1.f, 128, wsL3);
    wsplit_kernel<<<512, blk, 0, stream>>>(W4, sig + 3, 1.f, 256, wsL4);
    wsplit_kernel<<<32,  blk, 0, stream>>>(a1_qW, nullptr, LOG2E, 256, wsA1q);
    wsplit_kernel<<<32,  blk, 0, stream>>>(a1_kW, nullptr, 1.f, 256, wsA1k);
    wsplit_kernel<<<256, blk, 0, stream>>>(a1_vW, nullptr, 1.f, 256, wsA1v);
    wsplit_kernel<<<64,  blk, 0, stream>>>(a2_qW, nullptr, LOG2E, 512, wsA2q);
    wsplit_kernel<<<64,  blk, 0, stream>>>(a2_kW, nullptr, 1.f, 512, wsA2k);
    wsplit_kernel<<<512, blk, 0, stream>>>(a2_vW, nullptr, 1.f, 512, wsA2v);

    // L1 (fp32) + transpose/split
    conv_f32_kernel<<<dim3(64, 1, 4), blk, 0, stream>>>(x, W1, b1, sig + 0, h1, 6, 64, 1);
    tsplit64_kernel<<<dim3(64, 4), blk, 0, stream>>>(h1, h1t);

    // L2, L3 (split-MFMA, MF=1 -> doubled grids for latency hiding)
    mfma_conv<4, 1, 1, 2, 0, 1><<<dim3(32, 2, 4), blk, 0, stream>>>(h1t, wsL2, b2, 1.f, h2t, 64, 128);
    mfma_conv<4, 1, 1, 2, 0, 1><<<dim3(32, 4, 4), blk, 0, stream>>>(h2t, wsL3, b3, 1.f, h3t, 128, 256);

    // attention 1 (C=256, Cq=32): fused q|k projection -> (B,N,64)
    mfma_conv<2, 2, 1, 4, 0, 0><<<dim3(16, 2, 4), blk, 0, stream>>>(h3t, wsA1q, bbf, 1.f, qkt, 256, 64);
    mfma_conv<4, 1, 1, 1, 0, 0><<<dim3(32, 4, 4), blk, 0, stream>>>(h3t, wsA1v, a1_vb, 1.f, vb1, 256, 256);
    hipMemsetAsync(sums, 0, NF * sizeof(float), stream);
    s_gemm<32><<<dim3(32, 32, 4), blk, 0, stream>>>(qkt, qkt + 32, Sbuf, sums, 64);
    pv_gemm5<2><<<dim3(1024), blk, 0, stream>>>(Sbuf, vb1, sums, h3t, a1_g, h4t, 256);

    // L4 (fp32-transposed input)
    mfma_conv<4, 1, 1, 2, 1, 1><<<dim3(32, 8, 4), blk, 0, stream>>>(h4t, wsL4, b4, 1.f, h5t, 256, 512);

    // attention 2 (C=512, Cq=64): fused q|k projection -> (B,N,128)
    mfma_conv<2, 2, 1, 4, 0, 0><<<dim3(16, 4, 4), blk, 0, stream>>>(h5t, wsA2q, bbf + 64, 1.f, qkt, 512, 128);
    mfma_conv<4, 1, 1, 1, 0, 0><<<dim3(32, 8, 4), blk, 0, stream>>>(h5t, wsA2v, a2_vb, 1.f, vb2, 512, 512);
    hipMemsetAsync(sums, 0, NF * sizeof(float), stream);
    s_gemm<64><<<dim3(32, 32, 4), blk, 0, stream>>>(qkt, qkt + 64, Sbuf, sums, 128);
    pv_gemm5<4><<<dim3(1024), blk, 0, stream>>>(Sbuf, vb2, sums, h5t, a2_g, h6t, 512);

    // L5
    l5_kernel<<<4096, blk, 0, stream>>>(h6t, W5, b5, sig + 4, (float*)d_out);
}

// Round 17
// 771.440 us; speedup vs baseline: 1.2692x; 1.0429x over previous
//
#include <hip/hip_runtime.h>
#include <math.h>

#define N_PIX 4096  // H*W = 64*64
#define BATCH 4
#define LOG2E 1.4426950408889634f

typedef __bf16 bf16x8 __attribute__((ext_vector_type(8)));
typedef __bf16 bf16x4v __attribute__((ext_vector_type(4)));
typedef float f32x4 __attribute__((ext_vector_type(4)));

// ---------------------------------------------------------------------------
// Fused spectral norms: one block per layer, 1024 threads (16 waves).
// ---------------------------------------------------------------------------
struct SigP {
    const float* W[5];
    const float* u[5];
    int O[5];
    int C[5];
};

__global__ __launch_bounds__(1024)
void sigma_all(SigP p, float* __restrict__ out_inv) {
    __shared__ float ush[512];
    __shared__ float vsh[512];
    __shared__ float vpart[16 * 512];
    __shared__ float redl[1024];
    int L = blockIdx.x;
    const float* W = p.W[L];
    const float* u = p.u[L];
    int O = p.O[L], C = p.C[L];
    int t = threadIdx.x;
    int w = t >> 6, lane = t & 63;

    for (int i = t; i < O; i += 1024) ush[i] = u[i];
    __syncthreads();

    int o_beg = (O * w) >> 4, o_end = (O * (w + 1)) >> 4;
    for (int c = lane; c < C; c += 64) {
        float a = 0.f;
        for (int o = o_beg; o < o_end; ++o) a += W[(size_t)o * C + c] * ush[o];
        vpart[w * 512 + c] = a;
    }
    __syncthreads();

    float nn = 0.f;
    for (int c = t; c < C; c += 1024) {
        float s = 0.f;
        #pragma unroll
        for (int w2 = 0; w2 < 16; ++w2) s += vpart[w2 * 512 + c];
        vsh[c] = s;
        nn += s * s;
    }
    redl[t] = nn;
    __syncthreads();
    for (int s = 512; s > 0; s >>= 1) {
        if (t < s) redl[t] += redl[t + s];
        __syncthreads();
    }
    float nrm2 = redl[0];
    __syncthreads();
    float rinv = 1.f / (sqrtf(nrm2) + 1e-12f);

    float sq = 0.f;
    for (int o = w; o < O; o += 16) {
        float a = 0.f;
        for (int c = lane; c < C; c += 64) a += W[(size_t)o * C + c] * vsh[c];
        #pragma unroll
        for (int off = 1; off < 64; off <<= 1) a += __shfl_xor(a, off);
        if (lane == 0) sq += a * a;
    }
    if (lane == 0) redl[w] = sq;
    __syncthreads();
    if (t == 0) {
        float ns2raw = 0.f;
        #pragma unroll
        for (int i = 0; i < 16; ++i) ns2raw += redl[i];
        float ns2 = rinv * rinv * ns2raw;
        float sg = ns2 / (sqrtf(ns2) + 1e-12f);
        out_inv[L] = 1.f / sg;
    }
}

// ---------------------------------------------------------------------------
// Weight split: (O,C) fp32 * iv * scale -> (O, 2C) bf16  [hi | lo].
// ---------------------------------------------------------------------------
__global__ __launch_bounds__(256)
void wsplit_kernel(const float* __restrict__ W, const float* __restrict__ iv,
                   float scale, int C, __bf16* __restrict__ out) {
    int o = blockIdx.x;
    float s = (iv ? iv[0] : 1.f) * scale;
    for (int c = threadIdx.x; c < C; c += 256) {
        float wv = W[(size_t)o * C + c] * s;
        __bf16 hi = (__bf16)wv;
        float lo = wv - (float)hi;
        out[(size_t)o * 2 * C + c] = hi;
        out[(size_t)o * 2 * C + C + c] = (__bf16)lo;
    }
}

// ---------------------------------------------------------------------------
// Concat + prescale attention projection biases.
// ---------------------------------------------------------------------------
__global__ __launch_bounds__(256)
void concat_bias(const float* __restrict__ qb1, const float* __restrict__ kb1,
                 const float* __restrict__ qb2, const float* __restrict__ kb2,
                 float* __restrict__ bb) {
    int t = threadIdx.x;
    if (t < 32) bb[t] = qb1[t] * LOG2E;
    else if (t < 64) bb[t] = kb1[t - 32];
    else if (t < 128) bb[t] = qb2[t - 64] * LOG2E;
    else if (t < 192) bb[t] = kb2[t - 128];
}

// ---------------------------------------------------------------------------
// L1 only: fp32 VALU conv (C=6). x (B,C,N) -> out (B,O,N) fp32.
// ---------------------------------------------------------------------------
__global__ __launch_bounds__(256)
void conv_f32_kernel(const float* __restrict__ x, const float* __restrict__ W,
                     const float* __restrict__ bias, const float* __restrict__ sig,
                     float* __restrict__ out, int C, int O, int lrelu) {
    __shared__ float Ws[16][68];
    __shared__ float Xs[16][68];
    int t = threadIdx.x;
    int tx = t & 15, ty = t >> 4;
    int b = blockIdx.z;
    int n0 = blockIdx.x * 64, o0 = blockIdx.y * 64;
    float acc[4][4] = {};
    const float* xb = x + (size_t)b * C * N_PIX;
    for (int c0 = 0; c0 < C; c0 += 16) {
        #pragma unroll
        for (int i = 0; i < 4; ++i) {
            int e = t + i * 256;
            int o = e >> 4, c = e & 15;
            float wv = 0.f;
            if (o0 + o < O && c0 + c < C) wv = W[(size_t)(o0 + o) * C + c0 + c];
            Ws[c][o] = wv;
        }
        #pragma unroll
        for (int i = 0; i < 4; ++i) {
            int e = t + i * 256;
            int c = e >> 6, n = e & 63;
            float xv = 0.f;
            if (c0 + c < C) xv = xb[(size_t)(c0 + c) * N_PIX + n0 + n];
            Xs[c][n] = xv;
        }
        __syncthreads();
        #pragma unroll
        for (int cc = 0; cc < 16; ++cc) {
            float4 wv = *(const float4*)&Ws[cc][ty * 4];
            float4 xv = *(const float4*)&Xs[cc][tx * 4];
            float wa[4] = {wv.x, wv.y, wv.z, wv.w};
            float xa[4] = {xv.x, xv.y, xv.z, xv.w};
            #pragma unroll
            for (int i = 0; i < 4; ++i)
                #pragma unroll
                for (int j = 0; j < 4; ++j)
                    acc[i][j] += wa[i] * xa[j];
        }
        __syncthreads();
    }
    float ivv = sig ? sig[0] : 1.f;
    for (int i = 0; i < 4; ++i) {
        int o = o0 + ty * 4 + i;
        if (o >= O) break;
        float bv = bias[o];
        float vres[4];
        #pragma unroll
        for (int j = 0; j < 4; ++j) {
            float v = acc[i][j] * ivv + bv;
            if (lrelu) v = (v > 0.f) ? v : 0.1f * v;
            vres[j] = v;
        }
        *(float4*)&out[((size_t)b * O + o) * N_PIX + n0 + tx * 4] =
            make_float4(vres[0], vres[1], vres[2], vres[3]);
    }
}

// ---------------------------------------------------------------------------
// Transpose+split: (B,64,N) fp32 -> (B,N,128) bf16 [hi(64)|lo(64)].
// ---------------------------------------------------------------------------
__global__ __launch_bounds__(256)
void tsplit64_kernel(const float* __restrict__ in, __bf16* __restrict__ out) {
    __shared__ float tile[64 * 65];
    int t = threadIdx.x;
    int n0 = blockIdx.x * 64, b = blockIdx.y;
    for (int e = t; e < 64 * 64; e += 256) {
        int c = e >> 6, n = e & 63;
        tile[n * 65 + c] = in[((size_t)b * 64 + c) * N_PIX + n0 + n];
    }
    __syncthreads();
    for (int e = t; e < 64 * 64; e += 256) {
        int n = e >> 6, c = e & 63;
        float v = tile[n * 65 + c];
        __bf16 hi = (__bf16)v;
        size_t base = ((size_t)b * N_PIX + n0 + n) * 128;
        out[base + c] = hi;
        out[base + 64 + c] = (__bf16)(v - (float)hi);
    }
}

// ---------------------------------------------------------------------------
// Split-bf16 MFMA 1x1 conv. MF = m-frags per wave (1 or 2).
// ---------------------------------------------------------------------------
template <int WO, int WN, int MF, int MODE, int IN_F32, int LRELU>
__global__ __launch_bounds__(256)
void mfma_conv(const void* __restrict__ xt, const __bf16* __restrict__ wsp,
               const float* __restrict__ bias, float bscale,
               void* __restrict__ outp, int C, int O) {
    constexpr int NT_BLK = WN * 128;
    constexpr int OT_BLK = WO * 16 * MF;
    __shared__ __bf16 Ws[OT_BLK * 72];
    __shared__ __bf16 Xs[NT_BLK * 72];
    int t = threadIdx.x;
    int lane = t & 63, w = t >> 6;
    int l15 = lane & 15, quad = lane >> 4;
    int wo = w / WN, wn = w % WN;
    int b = blockIdx.z;
    int n0b = blockIdx.x * NT_BLK, o0b = blockIdx.y * OT_BLK;

    f32x4 acc[MF][8] = {};

    for (int c0 = 0; c0 < C; c0 += 32) {
        __syncthreads();
        for (int e = t; e < OT_BLK * 8; e += 256) {
            int row = e >> 3, part = e & 7;
            size_t src = (size_t)(o0b + row) * 2 * C +
                         (part < 4 ? c0 + part * 8 : C + c0 + (part - 4) * 8);
            int dst = row * 72 + (part < 4 ? part * 8 : 32 + (part - 4) * 8);
            *(uint4*)&Ws[dst] = *(const uint4*)&wsp[src];
        }
        if (IN_F32) {
            const float* xf = (const float*)xt;
            for (int e = t; e < NT_BLK * 8; e += 256) {
                int row = e >> 3, part = e & 7;
                float4 v = *(const float4*)&xf[((size_t)b * N_PIX + n0b + row) * C + c0 + part * 4];
                bf16x4v hi, lo;
                float va[4] = {v.x, v.y, v.z, v.w};
                #pragma unroll
                for (int j = 0; j < 4; ++j) {
                    hi[j] = (__bf16)va[j];
                    lo[j] = (__bf16)(va[j] - (float)hi[j]);
                }
                *(bf16x4v*)&Xs[row * 72 + part * 4] = hi;
                *(bf16x4v*)&Xs[row * 72 + 32 + part * 4] = lo;
            }
        } else {
            const __bf16* xb = (const __bf16*)xt;
            for (int e = t; e < NT_BLK * 8; e += 256) {
                int row = e >> 3, part = e & 7;
                size_t src = ((size_t)b * N_PIX + n0b + row) * 2 * C +
                             (part < 4 ? c0 + part * 8 : C + c0 + (part - 4) * 8);
                int dst = row * 72 + (part < 4 ? part * 8 : 32 + (part - 4) * 8);
                *(uint4*)&Xs[dst] = *(const uint4*)&xb[src];
            }
        }
        __syncthreads();

        bf16x8 ah[MF], al[MF];
        #pragma unroll
        for (int mf = 0; mf < MF; ++mf) {
            int base = (wo * 16 * MF + mf * 16 + l15) * 72 + quad * 8;
            ah[mf] = *(const bf16x8*)&Ws[base];
            al[mf] = *(const bf16x8*)&Ws[base + 32];
        }
        #pragma unroll
        for (int nt = 0; nt < 8; ++nt) {
            int bbase = (wn * 128 + nt * 16 + l15) * 72 + quad * 8;
            bf16x8 bh = *(const bf16x8*)&Xs[bbase];
            bf16x8 bl = *(const bf16x8*)&Xs[bbase + 32];
            #pragma unroll
            for (int mf = 0; mf < MF; ++mf) {
                acc[mf][nt] = __builtin_amdgcn_mfma_f32_16x16x32_bf16(ah[mf], bh, acc[mf][nt], 0, 0, 0);
                acc[mf][nt] = __builtin_amdgcn_mfma_f32_16x16x32_bf16(ah[mf], bl, acc[mf][nt], 0, 0, 0);
                acc[mf][nt] = __builtin_amdgcn_mfma_f32_16x16x32_bf16(al[mf], bh, acc[mf][nt], 0, 0, 0);
            }
        }
    }

    float bv[MF][4];
    #pragma unroll
    for (int mf = 0; mf < MF; ++mf)
        #pragma unroll
        for (int r = 0; r < 4; ++r)
            bv[mf][r] = bias[o0b + wo * 16 * MF + mf * 16 + quad * 4 + r] * bscale;

    #pragma unroll
    for (int mf = 0; mf < MF; ++mf)
        #pragma unroll
        for (int nt = 0; nt < 8; ++nt) {
            int n = n0b + wn * 128 + nt * 16 + l15;
            float val[4];
            #pragma unroll
            for (int r = 0; r < 4; ++r) {
                float v = acc[mf][nt][r] + bv[mf][r];
                if (LRELU) v = (v > 0.f) ? v : 0.1f * v;
                val[r] = v;
            }
            int obase = o0b + wo * 16 * MF + mf * 16 + quad * 4;
            if (MODE == 1) {
                __bf16* ob = (__bf16*)outp;
                #pragma unroll
                for (int r = 0; r < 4; ++r)
                    ob[((size_t)b * O + obase + r) * N_PIX + n] = (__bf16)val[r];
            } else if (MODE == 2) {
                __bf16* ob = (__bf16*)outp;
                bf16x4v hv, lv;
                #pragma unroll
                for (int r = 0; r < 4; ++r) {
                    hv[r] = (__bf16)val[r];
                    lv[r] = (__bf16)(val[r] - (float)hv[r]);
                }
                size_t rb = ((size_t)b * N_PIX + n) * 2 * O + obase;
                *(bf16x4v*)&ob[rb] = hv;
                *(bf16x4v*)&ob[rb + O] = lv;
            } else {  // MODE 4
                __bf16* ob = (__bf16*)outp;
                bf16x4v hv;
                #pragma unroll
                for (int r = 0; r < 4; ++r) hv[r] = (__bf16)val[r];
                *(bf16x4v*)&ob[((size_t)b * N_PIX + n) * O + obase] = hv;
            }
        }
}

// ---------------------------------------------------------------------------
// Attention kernel 1/2: E = exp2(qk-dot), bf16, + per-row atomic partial sums.
// ---------------------------------------------------------------------------
template <int CQ>
__global__ __launch_bounds__(256)
void s_gemm(const __bf16* __restrict__ qt, const __bf16* __restrict__ kt,
            __bf16* __restrict__ S, float* __restrict__ sums, int QSTR) {
    constexpr int NKK = CQ / 32;
    __shared__ __bf16 Ss[128 * 136];
    int t = threadIdx.x;
    int lane = t & 63, w = t >> 6;
    int l15 = lane & 15, quad = lane >> 4;
    int k0 = blockIdx.x * 128, q0 = blockIdx.y * 128, b = blockIdx.z;

    bf16x8 kf[2][NKK], qf[8][NKK];
    #pragma unroll
    for (int mf = 0; mf < 2; ++mf)
        #pragma unroll
        for (int kk = 0; kk < NKK; ++kk)
            kf[mf][kk] = *(const bf16x8*)&kt[((size_t)b * N_PIX + k0 + w * 32 + mf * 16 + l15) * QSTR + kk * 32 + quad * 8];
    #pragma unroll
    for (int nt = 0; nt < 8; ++nt)
        #pragma unroll
        for (int kk = 0; kk < NKK; ++kk)
            qf[nt][kk] = *(const bf16x8*)&qt[((size_t)b * N_PIX + q0 + nt * 16 + l15) * QSTR + kk * 32 + quad * 8];

    f32x4 acc[2][8] = {};
    #pragma unroll
    for (int kk = 0; kk < NKK; ++kk)
        #pragma unroll
        for (int mf = 0; mf < 2; ++mf)
            #pragma unroll
            for (int nt = 0; nt < 8; ++nt)
                acc[mf][nt] = __builtin_amdgcn_mfma_f32_16x16x32_bf16(kf[mf][kk], qf[nt][kk], acc[mf][nt], 0, 0, 0);

    #pragma unroll
    for (int mf = 0; mf < 2; ++mf)
        #pragma unroll
        for (int nt = 0; nt < 8; ++nt) {
            bf16x4v pk;
            #pragma unroll
            for (int r = 0; r < 4; ++r) pk[r] = (__bf16)exp2f(acc[mf][nt][r]);
            *(bf16x4v*)&Ss[(nt * 16 + l15) * 136 + w * 32 + mf * 16 + quad * 4] = pk;
        }
    __syncthreads();
    int ql = t >> 1, kh = (t & 1) * 64;
    size_t row = ((size_t)b * N_PIX + q0 + ql) * N_PIX + k0 + kh;
    float rs = 0.f;
    #pragma unroll
    for (int j = 0; j < 8; ++j) {
        bf16x8 v = *(const bf16x8*)&Ss[ql * 136 + kh + j * 8];
        #pragma unroll
        for (int e = 0; e < 8; ++e) rs += (float)v[e];
        *(bf16x8*)&S[row + j * 8] = v;
    }
    rs += __shfl_xor(rs, 1);
    if ((t & 1) == 0) atomicAdd(&sums[(size_t)b * N_PIX + q0 + ql], rs);
}

// ---------------------------------------------------------------------------
// Attention kernel 2/2: PV GEMM with ASYNC global_load_lds staging (width 16).
// LDS layout unpadded 64-elem rows + XOR swizzle: LDS[row][cg] holds
// G[row][cg ^ (row&7)] (cg = 16B column group 0..7).  Wave stages 1KB chunks
// (8 rows x 8 cg), lane i -> row i>>3, loads cg (i&7)^(i>>3); HW writes
// lane i at chunk_base + i*16 (wave-uniform dest per m104/m108).
// M=128, grid 1024 = 8 cblk x 128 pair, XCD-pinned (bid%8 == pair%8).
// ---------------------------------------------------------------------------
typedef __attribute__((address_space(1))) const void* gas1_t;
typedef __attribute__((address_space(3))) void* las3_t;

template <int NT>
__global__ __launch_bounds__(256)
void pv_gemm6(const __bf16* __restrict__ E, const __bf16* __restrict__ vg,
              const float* __restrict__ sums, const __bf16* __restrict__ xin2,
              const float* __restrict__ gamma, float* __restrict__ out, int C) {
    constexpr int CCH = NT * 16;
    __shared__ __bf16 Psh[128 * 64];
    __shared__ __bf16 Vsh[CCH * 64];
    __shared__ float ilsh[128];
    int t = threadIdx.x;
    int lane = t & 63, w = t >> 6;
    int l15 = lane & 15, quad = lane >> 4;
    int bid = blockIdx.x;
    int pair = bid & 127, cblk = bid >> 7;
    int qi = pair >> 2, b = pair & 3;
    int q0 = qi * 128, c0 = cblk * CCH;
    const __bf16* Pb = E + ((size_t)b * N_PIX + q0) * N_PIX;
    const __bf16* Vb = vg + ((size_t)b * C + c0) * N_PIX;

    if (t < 128) ilsh[t] = 1.f / sums[(size_t)b * N_PIX + q0 + t];

    int r8 = lane >> 3;           // row within chunk (0..7)
    int cgl = (lane & 7) ^ r8;    // swizzled column group to load

    f32x4 acc[2][NT] = {};

    for (int k0 = 0; k0 < N_PIX; k0 += 64) {
        __syncthreads();  // protect LDS from previous iteration's readers
        // stage P: wave w covers rows [w*32, w*32+32) in 4 x 1KB chunks
        #pragma unroll
        for (int ch = 0; ch < 4; ++ch) {
            int row0 = w * 32 + ch * 8;
            const __bf16* g = Pb + (size_t)(row0 + r8) * N_PIX + k0 + cgl * 8;
            __builtin_amdgcn_global_load_lds((gas1_t)g, (las3_t)&Psh[row0 * 64], 16, 0, 0);
        }
        // stage V: CCH rows in CCH/8 chunks spread over 4 waves
        #pragma unroll
        for (int ch = 0; ch < CCH / 32; ++ch) {
            int row0 = (w + ch * 4) * 8;
            const __bf16* g = Vb + (size_t)(row0 + r8) * N_PIX + k0 + cgl * 8;
            __builtin_amdgcn_global_load_lds((gas1_t)g, (las3_t)&Vsh[row0 * 64], 16, 0, 0);
        }
        __syncthreads();  // compiler drains vmcnt before barrier

        #pragma unroll
        for (int kk = 0; kk < 2; ++kk) {
            bf16x8 pa[2];
            #pragma unroll
            for (int mf = 0; mf < 2; ++mf) {
                int row = w * 32 + mf * 16 + l15;
                int cg = (kk * 4 + quad) ^ (row & 7);
                pa[mf] = *(const bf16x8*)&Psh[row * 64 + cg * 8];
            }
            #pragma unroll
            for (int nt = 0; nt < NT; ++nt) {
                int row = nt * 16 + l15;
                int cg = (kk * 4 + quad) ^ (row & 7);
                bf16x8 vf = *(const bf16x8*)&Vsh[row * 64 + cg * 8];
                #pragma unroll
                for (int mf = 0; mf < 2; ++mf)
                    acc[mf][nt] = __builtin_amdgcn_mfma_f32_16x16x32_bf16(pa[mf], vf, acc[mf][nt], 0, 0, 0);
            }
        }
    }

    float g = gamma[0];
    #pragma unroll
    for (int mf = 0; mf < 2; ++mf)
        #pragma unroll
        for (int r = 0; r < 4; ++r) {
            int ql = w * 32 + mf * 16 + quad * 4 + r;
            int q = q0 + ql;
            float gil = g * ilsh[ql];
            size_t xrb = ((size_t)b * N_PIX + q) * 2 * C;
            size_t orb = ((size_t)b * N_PIX + q) * C;
            #pragma unroll
            for (int nt = 0; nt < NT; ++nt) {
                int c = c0 + nt * 16 + l15;
                float xr = (float)xin2[xrb + c] + (float)xin2[xrb + C + c];
                out[orb + c] = gil * acc[mf][nt][r] + xr;
            }
        }
}

// ---------------------------------------------------------------------------
// L5: out[b,n] = lrelu(iv * dot(W5, h[b,n,:]) + b5).  h: (B,N,512) fp32.
// ---------------------------------------------------------------------------
__global__ __launch_bounds__(256)
void l5_kernel(const float* __restrict__ h, const float* __restrict__ W5,
               const float* __restrict__ b5, const float* __restrict__ sig,
               float* __restrict__ out) {
    int t = threadIdx.x;
    int lane = t & 63, w = t >> 6;
    int p = blockIdx.x * 4 + w;
    const float* row = h + (size_t)p * 512;
    float4 a0 = *(const float4*)&row[lane * 8];
    float4 a1 = *(const float4*)&row[lane * 8 + 4];
    float4 w0 = *(const float4*)&W5[lane * 8];
    float4 w1 = *(const float4*)&W5[lane * 8 + 4];
    float s = a0.x * w0.x + a0.y * w0.y + a0.z * w0.z + a0.w * w0.w +
              a1.x * w1.x + a1.y * w1.y + a1.z * w1.z + a1.w * w1.w;
    #pragma unroll
    for (int off = 1; off < 64; off <<= 1) s += __shfl_xor(s, off);
    if (lane == 0) {
        float v = sig[0] * s + b5[0];
        out[p] = (v > 0.f) ? v : 0.1f * v;
    }
}

// ---------------------------------------------------------------------------
// Launcher
// ---------------------------------------------------------------------------
extern "C" void kernel_launch(void* const* d_in, const int* in_sizes, int n_in,
                              void* d_out, int out_size, void* d_ws, size_t ws_size,
                              hipStream_t stream) {
    const float* x   = (const float*)d_in[0];
    const float* W1  = (const float*)d_in[1];
    const float* b1  = (const float*)d_in[2];
    const float* u1  = (const float*)d_in[3];
    const float* W2  = (const float*)d_in[4];
    const float* b2  = (const float*)d_in[5];
    const float* u2  = (const float*)d_in[6];
    const float* W3  = (const float*)d_in[7];
    const float* b3  = (const float*)d_in[8];
    const float* u3  = (const float*)d_in[9];
    const float* W4  = (const float*)d_in[10];
    const float* b4  = (const float*)d_in[11];
    const float* u4  = (const float*)d_in[12];
    const float* W5  = (const float*)d_in[13];
    const float* b5  = (const float*)d_in[14];
    const float* u5  = (const float*)d_in[15];
    const float* a1_qW = (const float*)d_in[16];
    const float* a1_qb = (const float*)d_in[17];
    const float* a1_kW = (const float*)d_in[18];
    const float* a1_kb = (const float*)d_in[19];
    const float* a1_vW = (const float*)d_in[20];
    const float* a1_vb = (const float*)d_in[21];
    const float* a1_g  = (const float*)d_in[22];
    const float* a2_qW = (const float*)d_in[23];
    const float* a2_qb = (const float*)d_in[24];
    const float* a2_kW = (const float*)d_in[25];
    const float* a2_kb = (const float*)d_in[26];
    const float* a2_vW = (const float*)d_in[27];
    const float* a2_vb = (const float*)d_in[28];
    const float* a2_g  = (const float*)d_in[29];

    float* ws = (float*)d_ws;
    const size_t NF = (size_t)BATCH * N_PIX;  // 16384
    float* sig    = ws;                       // 16
    float* h1     = ws + 16;                  // NF*64 fl (reused as sums)
    float* slabC  = h1 + NF * 64;             // NF*512 fl
    float* slabS1 = slabC + NF * 512;         // NF*256 fl
    float* slabS2 = slabS1 + NF * 256;        // NF*512 fl
    float* qtf    = slabS2 + NF * 512;        // NF*32 fl
    float* ktf    = qtf + NF * 32;            // NF*32 fl
    float* wspf   = ktf + NF * 32;            // ~0.6M fl
    float* bbf    = wspf + 592000;            // 192 fl bias concat
    float* Sf     = wspf + 600000;            // E: NF*4096 bf16

    __bf16* h1t = (__bf16*)slabS1;            // (B,N,128)
    __bf16* h2t = (__bf16*)slabS2;            // (B,N,256)
    __bf16* h3t = (__bf16*)slabS1;            // (B,N,512)
    __bf16* h5t = (__bf16*)slabS2;            // (B,N,1024)
    float*  h4t = slabC;                      // (B,N,256) fp32
    __bf16* vb1 = (__bf16*)(slabC + NF * 256);// (B,256,N)
    float*  h6t = slabC;                      // (B,N,512) fp32
    __bf16* vb2 = (__bf16*)slabS1;            // (B,512,N)
    __bf16* qkt = (__bf16*)qtf;               // (B,N,2CQ) packed [q|k]
    __bf16* wsp = (__bf16*)wspf;
    __bf16* Sbuf = (__bf16*)Sf;               // (B,4096,4096) bf16
    float*  sums = h1;                        // B*N floats (h1 dead after tsplit)

    __bf16* wsL2  = wsp;            // 128*128
    __bf16* wsL3  = wsL2 + 16384;   // 256*256
    __bf16* wsL4  = wsL3 + 65536;   // 512*512
    __bf16* wsA1q = wsL4 + 262144;  // 32*512   [combined with wsA1k: (64,512)]
    __bf16* wsA1k = wsA1q + 16384;
    __bf16* wsA1v = wsA1k + 16384;  // 256*512
    __bf16* wsA2q = wsA1v + 131072; // 64*1024  [combined with wsA2k: (128,1024)]
    __bf16* wsA2k = wsA2q + 65536;
    __bf16* wsA2v = wsA2k + 65536;  // 512*1024

    dim3 blk(256);

    SigP sp;
    sp.W[0] = W1; sp.u[0] = u1; sp.O[0] = 64;  sp.C[0] = 6;
    sp.W[1] = W2; sp.u[1] = u2; sp.O[1] = 128; sp.C[1] = 64;
    sp.W[2] = W3; sp.u[2] = u3; sp.O[2] = 256; sp.C[2] = 128;
    sp.W[3] = W4; sp.u[3] = u4; sp.O[3] = 512; sp.C[3] = 256;
    sp.W[4] = W5; sp.u[4] = u5; sp.O[4] = 1;   sp.C[4] = 512;
    sigma_all<<<dim3(5), dim3(1024), 0, stream>>>(sp, sig);

    concat_bias<<<1, blk, 0, stream>>>(a1_qb, a1_kb, a2_qb, a2_kb, bbf);

    wsplit_kernel<<<128, blk, 0, stream>>>(W2, sig + 1, 1.f, 64, wsL2);
    wsplit_kernel<<<256, blk, 0, stream>>>(W3, sig + 2, 1.f, 128, wsL3);
    wsplit_kernel<<<512, blk, 0, stream>>>(W4, sig + 3, 1.f, 256, wsL4);
    wsplit_kernel<<<32,  blk, 0, stream>>>(a1_qW, nullptr, LOG2E, 256, wsA1q);
    wsplit_kernel<<<32,  blk, 0, stream>>>(a1_kW, nullptr, 1.f, 256, wsA1k);
    wsplit_kernel<<<256, blk, 0, stream>>>(a1_vW, nullptr, 1.f, 256, wsA1v);
    wsplit_kernel<<<64,  blk, 0, stream>>>(a2_qW, nullptr, LOG2E, 512, wsA2q);
    wsplit_kernel<<<64,  blk, 0, stream>>>(a2_kW, nullptr, 1.f, 512, wsA2k);
    wsplit_kernel<<<512, blk, 0, stream>>>(a2_vW, nullptr, 1.f, 512, wsA2v);

    // L1 (fp32) + transpose/split
    conv_f32_kernel<<<dim3(64, 1, 4), blk, 0, stream>>>(x, W1, b1, sig + 0, h1, 6, 64, 1);
    tsplit64_kernel<<<dim3(64, 4), blk, 0, stream>>>(h1, h1t);

    // L2, L3 (split-MFMA, MF=1)
    mfma_conv<4, 1, 1, 2, 0, 1><<<dim3(32, 2, 4), blk, 0, stream>>>(h1t, wsL2, b2, 1.f, h2t, 64, 128);
    mfma_conv<4, 1, 1, 2, 0, 1><<<dim3(32, 4, 4), blk, 0, stream>>>(h2t, wsL3, b3, 1.f, h3t, 128, 256);

    // attention 1 (C=256, Cq=32): fused q|k projection -> (B,N,64)
    mfma_conv<2, 2, 1, 4, 0, 0><<<dim3(16, 2, 4), blk, 0, stream>>>(h3t, wsA1q, bbf, 1.f, qkt, 256, 64);
    mfma_conv<4, 1, 1, 1, 0, 0><<<dim3(32, 4, 4), blk, 0, stream>>>(h3t, wsA1v, a1_vb, 1.f, vb1, 256, 256);
    hipMemsetAsync(sums, 0, NF * sizeof(float), stream);
    s_gemm<32><<<dim3(32, 32, 4), blk, 0, stream>>>(qkt, qkt + 32, Sbuf, sums, 64);
    pv_gemm6<2><<<dim3(1024), blk, 0, stream>>>(Sbuf, vb1, sums, h3t, a1_g, h4t, 256);

    // L4 (fp32-transposed input)
    mfma_conv<4, 1, 1, 2, 1, 1><<<dim3(32, 8, 4), blk, 0, stream>>>(h4t, wsL4, b4, 1.f, h5t, 256, 512);

    // attention 2 (C=512, Cq=64): fused q|k projection -> (B,N,128)
    mfma_conv<2, 2, 1, 4, 0, 0><<<dim3(16, 4, 4), blk, 0, stream>>>(h5t, wsA2q, bbf + 64, 1.f, qkt, 512, 128);
    mfma_conv<4, 1, 1, 1, 0, 0><<<dim3(32, 8, 4), blk, 0, stream>>>(h5t, wsA2v, a2_vb, 1.f, vb2, 512, 512);
    hipMemsetAsync(sums, 0, NF * sizeof(float), stream);
    s_gemm<64><<<dim3(32, 32, 4), blk, 0, stream>>>(qkt, qkt + 64, Sbuf, sums, 128);
    pv_gemm6<4><<<dim3(1024), blk, 0, stream>>>(Sbuf, vb2, sums, h5t, a2_g, h6t, 512);

    // L5
    l5_kernel<<<4096, blk, 0, stream>>>(h6t, W5, b5, sig + 4, (float*)d_out);
}

// Round 18
// 634.952 us; speedup vs baseline: 1.5420x; 1.2150x over previous
//
#include <hip/hip_runtime.h>
#include <math.h>

#define N_PIX 4096  // H*W = 64*64
#define BATCH 4
#define LOG2E 1.4426950408889634f

typedef __bf16 bf16x8 __attribute__((ext_vector_type(8)));
typedef __bf16 bf16x4v __attribute__((ext_vector_type(4)));
typedef float f32x4 __attribute__((ext_vector_type(4)));

// fp8 e4m3 (OCP on gfx950) pack/unpack via HW cvt builtins
__device__ __forceinline__ unsigned pack4_fp8(float a, float b, float c, float d) {
    unsigned p = __builtin_amdgcn_cvt_pk_fp8_f32(a, b, 0, false);
    p = __builtin_amdgcn_cvt_pk_fp8_f32(c, d, p, true);
    return p;
}
__device__ __forceinline__ uint8_t to_fp8(float v) {
    return (uint8_t)(__builtin_amdgcn_cvt_pk_fp8_f32(v, v, 0, false) & 0xff);
}

// ---------------------------------------------------------------------------
// Fused spectral norms: one block per layer, 1024 threads (16 waves).
// ---------------------------------------------------------------------------
struct SigP {
    const float* W[5];
    const float* u[5];
    int O[5];
    int C[5];
};

__global__ __launch_bounds__(1024)
void sigma_all(SigP p, float* __restrict__ out_inv) {
    __shared__ float ush[512];
    __shared__ float vsh[512];
    __shared__ float vpart[16 * 512];
    __shared__ float redl[1024];
    int L = blockIdx.x;
    const float* W = p.W[L];
    const float* u = p.u[L];
    int O = p.O[L], C = p.C[L];
    int t = threadIdx.x;
    int w = t >> 6, lane = t & 63;

    for (int i = t; i < O; i += 1024) ush[i] = u[i];
    __syncthreads();

    int o_beg = (O * w) >> 4, o_end = (O * (w + 1)) >> 4;
    for (int c = lane; c < C; c += 64) {
        float a = 0.f;
        for (int o = o_beg; o < o_end; ++o) a += W[(size_t)o * C + c] * ush[o];
        vpart[w * 512 + c] = a;
    }
    __syncthreads();

    float nn = 0.f;
    for (int c = t; c < C; c += 1024) {
        float s = 0.f;
        #pragma unroll
        for (int w2 = 0; w2 < 16; ++w2) s += vpart[w2 * 512 + c];
        vsh[c] = s;
        nn += s * s;
    }
    redl[t] = nn;
    __syncthreads();
    for (int s = 512; s > 0; s >>= 1) {
        if (t < s) redl[t] += redl[t + s];
        __syncthreads();
    }
    float nrm2 = redl[0];
    __syncthreads();
    float rinv = 1.f / (sqrtf(nrm2) + 1e-12f);

    float sq = 0.f;
    for (int o = w; o < O; o += 16) {
        float a = 0.f;
        for (int c = lane; c < C; c += 64) a += W[(size_t)o * C + c] * vsh[c];
        #pragma unroll
        for (int off = 1; off < 64; off <<= 1) a += __shfl_xor(a, off);
        if (lane == 0) sq += a * a;
    }
    if (lane == 0) redl[w] = sq;
    __syncthreads();
    if (t == 0) {
        float ns2raw = 0.f;
        #pragma unroll
        for (int i = 0; i < 16; ++i) ns2raw += redl[i];
        float ns2 = rinv * rinv * ns2raw;
        float sg = ns2 / (sqrtf(ns2) + 1e-12f);
        out_inv[L] = 1.f / sg;
    }
}

// ---------------------------------------------------------------------------
// Weight split: (O,C) fp32 * iv * scale -> (O, 2C) bf16  [hi | lo].
// ---------------------------------------------------------------------------
__global__ __launch_bounds__(256)
void wsplit_kernel(const float* __restrict__ W, const float* __restrict__ iv,
                   float scale, int C, __bf16* __restrict__ out) {
    int o = blockIdx.x;
    float s = (iv ? iv[0] : 1.f) * scale;
    for (int c = threadIdx.x; c < C; c += 256) {
        float wv = W[(size_t)o * C + c] * s;
        __bf16 hi = (__bf16)wv;
        float lo = wv - (float)hi;
        out[(size_t)o * 2 * C + c] = hi;
        out[(size_t)o * 2 * C + C + c] = (__bf16)lo;
    }
}

// ---------------------------------------------------------------------------
// Concat + prescale attention projection biases.
// ---------------------------------------------------------------------------
__global__ __launch_bounds__(256)
void concat_bias(const float* __restrict__ qb1, const float* __restrict__ kb1,
                 const float* __restrict__ qb2, const float* __restrict__ kb2,
                 float* __restrict__ bb) {
    int t = threadIdx.x;
    if (t < 32) bb[t] = qb1[t] * LOG2E;
    else if (t < 64) bb[t] = kb1[t - 32];
    else if (t < 128) bb[t] = qb2[t - 64] * LOG2E;
    else if (t < 192) bb[t] = kb2[t - 128];
}

// ---------------------------------------------------------------------------
// L1 only: fp32 VALU conv (C=6). x (B,C,N) -> out (B,O,N) fp32.
// ---------------------------------------------------------------------------
__global__ __launch_bounds__(256)
void conv_f32_kernel(const float* __restrict__ x, const float* __restrict__ W,
                     const float* __restrict__ bias, const float* __restrict__ sig,
                     float* __restrict__ out, int C, int O, int lrelu) {
    __shared__ float Ws[16][68];
    __shared__ float Xs[16][68];
    int t = threadIdx.x;
    int tx = t & 15, ty = t >> 4;
    int b = blockIdx.z;
    int n0 = blockIdx.x * 64, o0 = blockIdx.y * 64;
    float acc[4][4] = {};
    const float* xb = x + (size_t)b * C * N_PIX;
    for (int c0 = 0; c0 < C; c0 += 16) {
        #pragma unroll
        for (int i = 0; i < 4; ++i) {
            int e = t + i * 256;
            int o = e >> 4, c = e & 15;
            float wv = 0.f;
            if (o0 + o < O && c0 + c < C) wv = W[(size_t)(o0 + o) * C + c0 + c];
            Ws[c][o] = wv;
        }
        #pragma unroll
        for (int i = 0; i < 4; ++i) {
            int e = t + i * 256;
            int c = e >> 6, n = e & 63;
            float xv = 0.f;
            if (c0 + c < C) xv = xb[(size_t)(c0 + c) * N_PIX + n0 + n];
            Xs[c][n] = xv;
        }
        __syncthreads();
        #pragma unroll
        for (int cc = 0; cc < 16; ++cc) {
            float4 wv = *(const float4*)&Ws[cc][ty * 4];
            float4 xv = *(const float4*)&Xs[cc][tx * 4];
            float wa[4] = {wv.x, wv.y, wv.z, wv.w};
            float xa[4] = {xv.x, xv.y, xv.z, xv.w};
            #pragma unroll
            for (int i = 0; i < 4; ++i)
                #pragma unroll
                for (int j = 0; j < 4; ++j)
                    acc[i][j] += wa[i] * xa[j];
        }
        __syncthreads();
    }
    float ivv = sig ? sig[0] : 1.f;
    for (int i = 0; i < 4; ++i) {
        int o = o0 + ty * 4 + i;
        if (o >= O) break;
        float bv = bias[o];
        float vres[4];
        #pragma unroll
        for (int j = 0; j < 4; ++j) {
            float v = acc[i][j] * ivv + bv;
            if (lrelu) v = (v > 0.f) ? v : 0.1f * v;
            vres[j] = v;
        }
        *(float4*)&out[((size_t)b * O + o) * N_PIX + n0 + tx * 4] =
            make_float4(vres[0], vres[1], vres[2], vres[3]);
    }
}

// ---------------------------------------------------------------------------
// Transpose+split: (B,64,N) fp32 -> (B,N,128) bf16 [hi(64)|lo(64)].
// ---------------------------------------------------------------------------
__global__ __launch_bounds__(256)
void tsplit64_kernel(const float* __restrict__ in, __bf16* __restrict__ out) {
    __shared__ float tile[64 * 65];
    int t = threadIdx.x;
    int n0 = blockIdx.x * 64, b = blockIdx.y;
    for (int e = t; e < 64 * 64; e += 256) {
        int c = e >> 6, n = e & 63;
        tile[n * 65 + c] = in[((size_t)b * 64 + c) * N_PIX + n0 + n];
    }
    __syncthreads();
    for (int e = t; e < 64 * 64; e += 256) {
        int n = e >> 6, c = e & 63;
        float v = tile[n * 65 + c];
        __bf16 hi = (__bf16)v;
        size_t base = ((size_t)b * N_PIX + n0 + n) * 128;
        out[base + c] = hi;
        out[base + 64 + c] = (__bf16)(v - (float)hi);
    }
}

// ---------------------------------------------------------------------------
// Split-bf16 MFMA 1x1 conv. MF = m-frags per wave (1 or 2).
// MODE 1 now emits fp8-e4m3 (B,O,N) for the attention V buffers.
// ---------------------------------------------------------------------------
template <int WO, int WN, int MF, int MODE, int IN_F32, int LRELU>
__global__ __launch_bounds__(256)
void mfma_conv(const void* __restrict__ xt, const __bf16* __restrict__ wsp,
               const float* __restrict__ bias, float bscale,
               void* __restrict__ outp, int C, int O) {
    constexpr int NT_BLK = WN * 128;
    constexpr int OT_BLK = WO * 16 * MF;
    __shared__ __bf16 Ws[OT_BLK * 72];
    __shared__ __bf16 Xs[NT_BLK * 72];
    int t = threadIdx.x;
    int lane = t & 63, w = t >> 6;
    int l15 = lane & 15, quad = lane >> 4;
    int wo = w / WN, wn = w % WN;
    int b = blockIdx.z;
    int n0b = blockIdx.x * NT_BLK, o0b = blockIdx.y * OT_BLK;

    f32x4 acc[MF][8] = {};

    for (int c0 = 0; c0 < C; c0 += 32) {
        __syncthreads();
        for (int e = t; e < OT_BLK * 8; e += 256) {
            int row = e >> 3, part = e & 7;
            size_t src = (size_t)(o0b + row) * 2 * C +
                         (part < 4 ? c0 + part * 8 : C + c0 + (part - 4) * 8);
            int dst = row * 72 + (part < 4 ? part * 8 : 32 + (part - 4) * 8);
            *(uint4*)&Ws[dst] = *(const uint4*)&wsp[src];
        }
        if (IN_F32) {
            const float* xf = (const float*)xt;
            for (int e = t; e < NT_BLK * 8; e += 256) {
                int row = e >> 3, part = e & 7;
                float4 v = *(const float4*)&xf[((size_t)b * N_PIX + n0b + row) * C + c0 + part * 4];
                bf16x4v hi, lo;
                float va[4] = {v.x, v.y, v.z, v.w};
                #pragma unroll
                for (int j = 0; j < 4; ++j) {
                    hi[j] = (__bf16)va[j];
                    lo[j] = (__bf16)(va[j] - (float)hi[j]);
                }
                *(bf16x4v*)&Xs[row * 72 + part * 4] = hi;
                *(bf16x4v*)&Xs[row * 72 + 32 + part * 4] = lo;
            }
        } else {
            const __bf16* xb = (const __bf16*)xt;
            for (int e = t; e < NT_BLK * 8; e += 256) {
                int row = e >> 3, part = e & 7;
                size_t src = ((size_t)b * N_PIX + n0b + row) * 2 * C +
                             (part < 4 ? c0 + part * 8 : C + c0 + (part - 4) * 8);
                int dst = row * 72 + (part < 4 ? part * 8 : 32 + (part - 4) * 8);
                *(uint4*)&Xs[dst] = *(const uint4*)&xb[src];
            }
        }
        __syncthreads();

        bf16x8 ah[MF], al[MF];
        #pragma unroll
        for (int mf = 0; mf < MF; ++mf) {
            int base = (wo * 16 * MF + mf * 16 + l15) * 72 + quad * 8;
            ah[mf] = *(const bf16x8*)&Ws[base];
            al[mf] = *(const bf16x8*)&Ws[base + 32];
        }
        #pragma unroll
        for (int nt = 0; nt < 8; ++nt) {
            int bbase = (wn * 128 + nt * 16 + l15) * 72 + quad * 8;
            bf16x8 bh = *(const bf16x8*)&Xs[bbase];
            bf16x8 bl = *(const bf16x8*)&Xs[bbase + 32];
            #pragma unroll
            for (int mf = 0; mf < MF; ++mf) {
                acc[mf][nt] = __builtin_amdgcn_mfma_f32_16x16x32_bf16(ah[mf], bh, acc[mf][nt], 0, 0, 0);
                acc[mf][nt] = __builtin_amdgcn_mfma_f32_16x16x32_bf16(ah[mf], bl, acc[mf][nt], 0, 0, 0);
                acc[mf][nt] = __builtin_amdgcn_mfma_f32_16x16x32_bf16(al[mf], bh, acc[mf][nt], 0, 0, 0);
            }
        }
    }

    float bv[MF][4];
    #pragma unroll
    for (int mf = 0; mf < MF; ++mf)
        #pragma unroll
        for (int r = 0; r < 4; ++r)
            bv[mf][r] = bias[o0b + wo * 16 * MF + mf * 16 + quad * 4 + r] * bscale;

    #pragma unroll
    for (int mf = 0; mf < MF; ++mf)
        #pragma unroll
        for (int nt = 0; nt < 8; ++nt) {
            int n = n0b + wn * 128 + nt * 16 + l15;
            float val[4];
            #pragma unroll
            for (int r = 0; r < 4; ++r) {
                float v = acc[mf][nt][r] + bv[mf][r];
                if (LRELU) v = (v > 0.f) ? v : 0.1f * v;
                val[r] = v;
            }
            int obase = o0b + wo * 16 * MF + mf * 16 + quad * 4;
            if (MODE == 1) {  // fp8 (B,O,N) for attention V
                uint8_t* ob = (uint8_t*)outp;
                #pragma unroll
                for (int r = 0; r < 4; ++r)
                    ob[((size_t)b * O + obase + r) * N_PIX + n] = to_fp8(val[r]);
            } else if (MODE == 2) {
                __bf16* ob = (__bf16*)outp;
                bf16x4v hv, lv;
                #pragma unroll
                for (int r = 0; r < 4; ++r) {
                    hv[r] = (__bf16)val[r];
                    lv[r] = (__bf16)(val[r] - (float)hv[r]);
                }
                size_t rb = ((size_t)b * N_PIX + n) * 2 * O + obase;
                *(bf16x4v*)&ob[rb] = hv;
                *(bf16x4v*)&ob[rb + O] = lv;
            } else {  // MODE 4
                __bf16* ob = (__bf16*)outp;
                bf16x4v hv;
                #pragma unroll
                for (int r = 0; r < 4; ++r) hv[r] = (__bf16)val[r];
                *(bf16x4v*)&ob[((size_t)b * N_PIX + n) * O + obase] = hv;
            }
        }
}

// ---------------------------------------------------------------------------
// Attention kernel 1/2: E = exp2(qk-dot) -> FP8-e4m3, + per-row atomic sums
// (sums computed from the fp8-rounded values so pv normalization is exact).
// ---------------------------------------------------------------------------
template <int CQ>
__global__ __launch_bounds__(256)
void s_gemm(const __bf16* __restrict__ qt, const __bf16* __restrict__ kt,
            uint8_t* __restrict__ S, float* __restrict__ sums, int QSTR) {
    constexpr int NKK = CQ / 32;
    __shared__ uint8_t Ss[128 * 144];
    int t = threadIdx.x;
    int lane = t & 63, w = t >> 6;
    int l15 = lane & 15, quad = lane >> 4;
    int k0 = blockIdx.x * 128, q0 = blockIdx.y * 128, b = blockIdx.z;

    bf16x8 kf[2][NKK], qf[8][NKK];
    #pragma unroll
    for (int mf = 0; mf < 2; ++mf)
        #pragma unroll
        for (int kk = 0; kk < NKK; ++kk)
            kf[mf][kk] = *(const bf16x8*)&kt[((size_t)b * N_PIX + k0 + w * 32 + mf * 16 + l15) * QSTR + kk * 32 + quad * 8];
    #pragma unroll
    for (int nt = 0; nt < 8; ++nt)
        #pragma unroll
        for (int kk = 0; kk < NKK; ++kk)
            qf[nt][kk] = *(const bf16x8*)&qt[((size_t)b * N_PIX + q0 + nt * 16 + l15) * QSTR + kk * 32 + quad * 8];

    f32x4 acc[2][8] = {};
    #pragma unroll
    for (int kk = 0; kk < NKK; ++kk)
        #pragma unroll
        for (int mf = 0; mf < 2; ++mf)
            #pragma unroll
            for (int nt = 0; nt < 8; ++nt)
                acc[mf][nt] = __builtin_amdgcn_mfma_f32_16x16x32_bf16(kf[mf][kk], qf[nt][kk], acc[mf][nt], 0, 0, 0);

    #pragma unroll
    for (int mf = 0; mf < 2; ++mf)
        #pragma unroll
        for (int nt = 0; nt < 8; ++nt) {
            unsigned p = pack4_fp8(exp2f(acc[mf][nt][0]), exp2f(acc[mf][nt][1]),
                                   exp2f(acc[mf][nt][2]), exp2f(acc[mf][nt][3]));
            *(unsigned*)&Ss[(nt * 16 + l15) * 144 + w * 32 + mf * 16 + quad * 4] = p;
        }
    __syncthreads();
    // coalesced fp8 write + per-row partial sum (this block's 128 keys)
    int ql = t >> 1, kh = (t & 1) * 64;
    size_t row = ((size_t)b * N_PIX + q0 + ql) * (size_t)N_PIX + k0 + kh;
    float rs = 0.f;
    #pragma unroll
    for (int j = 0; j < 4; ++j) {
        uint4 v = *(const uint4*)&Ss[ql * 144 + kh + j * 16];
        unsigned wds[4] = {v.x, v.y, v.z, v.w};
        #pragma unroll
        for (int q4 = 0; q4 < 4; ++q4) {
            rs += __builtin_amdgcn_cvt_f32_fp8(wds[q4], 0);
            rs += __builtin_amdgcn_cvt_f32_fp8(wds[q4], 1);
            rs += __builtin_amdgcn_cvt_f32_fp8(wds[q4], 2);
            rs += __builtin_amdgcn_cvt_f32_fp8(wds[q4], 3);
        }
        *(uint4*)&S[row + j * 16] = v;
    }
    rs += __shfl_xor(rs, 1);
    if ((t & 1) == 0) atomicAdd(&sums[(size_t)b * N_PIX + q0 + ql], rs);
}

// ---------------------------------------------------------------------------
// Attention kernel 2/2: FP8 PV GEMM, async global_load_lds staging, KT=128.
// LDS rows 128B (128 fp8 keys), 8 x 16B col-groups, XOR swizzle cg^(row&7).
// A/B frags: 8 fp8 (long) at byte kk*32+quad*8 -> cg=2kk+(quad>>1), +8*(quad&1).
// M=128, grid 1024 = 8 cblk x 128 pair, XCD-pinned (bid%8 == pair%8).
// ---------------------------------------------------------------------------
typedef __attribute__((address_space(1))) const void* gas1_t;
typedef __attribute__((address_space(3))) void* las3_t;

template <int NT>
__global__ __launch_bounds__(256)
void pv_gemm7(const uint8_t* __restrict__ E, const uint8_t* __restrict__ vg,
              const float* __restrict__ sums, const __bf16* __restrict__ xin2,
              const float* __restrict__ gamma, float* __restrict__ out, int C) {
    constexpr int CCH = NT * 16;
    __shared__ uint8_t Psh[128 * 128];
    __shared__ uint8_t Vsh[CCH * 128];
    __shared__ float ilsh[128];
    int t = threadIdx.x;
    int lane = t & 63, w = t >> 6;
    int l15 = lane & 15, quad = lane >> 4;
    int bid = blockIdx.x;
    int pair = bid & 127, cblk = bid >> 7;
    int qi = pair >> 2, b = pair & 3;
    int q0 = qi * 128, c0 = cblk * CCH;
    const uint8_t* Pb = E + ((size_t)b * N_PIX + q0) * (size_t)N_PIX;
    const uint8_t* Vb = vg + ((size_t)b * C + c0) * (size_t)N_PIX;

    if (t < 128) ilsh[t] = 1.f / sums[(size_t)b * N_PIX + q0 + t];

    int r8 = lane >> 3;           // row within 8-row chunk
    int cgl = (lane & 7) ^ r8;    // swizzled 16B column group to load

    f32x4 acc[2][NT] = {};

    for (int k0 = 0; k0 < N_PIX; k0 += 128) {
        __syncthreads();
        // stage P: wave w rows [w*32, w*32+32), 4 chunks of 8 rows x 128B
        #pragma unroll
        for (int ch = 0; ch < 4; ++ch) {
            int row0 = w * 32 + ch * 8;
            const uint8_t* g = Pb + (size_t)(row0 + r8) * N_PIX + k0 + cgl * 16;
            __builtin_amdgcn_global_load_lds((gas1_t)g, (las3_t)&Psh[row0 * 128], 16, 0, 0);
        }
        // stage V: CCH rows in CCH/8 chunks spread over 4 waves
        #pragma unroll
        for (int ch = 0; ch < CCH / 32; ++ch) {
            int row0 = (w + ch * 4) * 8;
            const uint8_t* g = Vb + (size_t)(row0 + r8) * N_PIX + k0 + cgl * 16;
            __builtin_amdgcn_global_load_lds((gas1_t)g, (las3_t)&Vsh[row0 * 128], 16, 0, 0);
        }
        __syncthreads();  // drains vmcnt

        #pragma unroll
        for (int kk = 0; kk < 4; ++kk) {
            long pa[2];
            #pragma unroll
            for (int mf = 0; mf < 2; ++mf) {
                int row = w * 32 + mf * 16 + l15;
                int cg = (2 * kk + (quad >> 1)) ^ (row & 7);
                pa[mf] = *(const long*)&Psh[row * 128 + cg * 16 + (quad & 1) * 8];
            }
            #pragma unroll
            for (int nt = 0; nt < NT; ++nt) {
                int row = nt * 16 + l15;
                int cg = (2 * kk + (quad >> 1)) ^ (row & 7);
                long vf = *(const long*)&Vsh[row * 128 + cg * 16 + (quad & 1) * 8];
                #pragma unroll
                for (int mf = 0; mf < 2; ++mf)
                    acc[mf][nt] = __builtin_amdgcn_mfma_f32_16x16x32_fp8_fp8(pa[mf], vf, acc[mf][nt], 0, 0, 0);
            }
        }
    }

    float g = gamma[0];
    #pragma unroll
    for (int mf = 0; mf < 2; ++mf)
        #pragma unroll
        for (int r = 0; r < 4; ++r) {
            int ql = w * 32 + mf * 16 + quad * 4 + r;
            int q = q0 + ql;
            float gil = g * ilsh[ql];
            size_t xrb = ((size_t)b * N_PIX + q) * 2 * C;
            size_t orb = ((size_t)b * N_PIX + q) * C;
            #pragma unroll
            for (int nt = 0; nt < NT; ++nt) {
                int c = c0 + nt * 16 + l15;
                float xr = (float)xin2[xrb + c] + (float)xin2[xrb + C + c];
                out[orb + c] = gil * acc[mf][nt][r] + xr;
            }
        }
}

// ---------------------------------------------------------------------------
// L5: out[b,n] = lrelu(iv * dot(W5, h[b,n,:]) + b5).  h: (B,N,512) fp32.
// ---------------------------------------------------------------------------
__global__ __launch_bounds__(256)
void l5_kernel(const float* __restrict__ h, const float* __restrict__ W5,
               const float* __restrict__ b5, const float* __restrict__ sig,
               float* __restrict__ out) {
    int t = threadIdx.x;
    int lane = t & 63, w = t >> 6;
    int p = blockIdx.x * 4 + w;
    const float* row = h + (size_t)p * 512;
    float4 a0 = *(const float4*)&row[lane * 8];
    float4 a1 = *(const float4*)&row[lane * 8 + 4];
    float4 w0 = *(const float4*)&W5[lane * 8];
    float4 w1 = *(const float4*)&W5[lane * 8 + 4];
    float s = a0.x * w0.x + a0.y * w0.y + a0.z * w0.z + a0.w * w0.w +
              a1.x * w1.x + a1.y * w1.y + a1.z * w1.z + a1.w * w1.w;
    #pragma unroll
    for (int off = 1; off < 64; off <<= 1) s += __shfl_xor(s, off);
    if (lane == 0) {
        float v = sig[0] * s + b5[0];
        out[p] = (v > 0.f) ? v : 0.1f * v;
    }
}

// ---------------------------------------------------------------------------
// Launcher
// ---------------------------------------------------------------------------
extern "C" void kernel_launch(void* const* d_in, const int* in_sizes, int n_in,
                              void* d_out, int out_size, void* d_ws, size_t ws_size,
                              hipStream_t stream) {
    const float* x   = (const float*)d_in[0];
    const float* W1  = (const float*)d_in[1];
    const float* b1  = (const float*)d_in[2];
    const float* u1  = (const float*)d_in[3];
    const float* W2  = (const float*)d_in[4];
    const float* b2  = (const float*)d_in[5];
    const float* u2  = (const float*)d_in[6];
    const float* W3  = (const float*)d_in[7];
    const float* b3  = (const float*)d_in[8];
    const float* u3  = (const float*)d_in[9];
    const float* W4  = (const float*)d_in[10];
    const float* b4  = (const float*)d_in[11];
    const float* u4  = (const float*)d_in[12];
    const float* W5  = (const float*)d_in[13];
    const float* b5  = (const float*)d_in[14];
    const float* u5  = (const float*)d_in[15];
    const float* a1_qW = (const float*)d_in[16];
    const float* a1_qb = (const float*)d_in[17];
    const float* a1_kW = (const float*)d_in[18];
    const float* a1_kb = (const float*)d_in[19];
    const float* a1_vW = (const float*)d_in[20];
    const float* a1_vb = (const float*)d_in[21];
    const float* a1_g  = (const float*)d_in[22];
    const float* a2_qW = (const float*)d_in[23];
    const float* a2_qb = (const float*)d_in[24];
    const float* a2_kW = (const float*)d_in[25];
    const float* a2_kb = (const float*)d_in[26];
    const float* a2_vW = (const float*)d_in[27];
    const float* a2_vb = (const float*)d_in[28];
    const float* a2_g  = (const float*)d_in[29];

    float* ws = (float*)d_ws;
    const size_t NF = (size_t)BATCH * N_PIX;  // 16384
    float* sig    = ws;                       // 16
    float* h1     = ws + 16;                  // NF*64 fl (reused as sums)
    float* slabC  = h1 + NF * 64;             // NF*512 fl
    float* slabS1 = slabC + NF * 512;         // NF*256 fl
    float* slabS2 = slabS1 + NF * 256;        // NF*512 fl
    float* qtf    = slabS2 + NF * 512;        // NF*32 fl
    float* ktf    = qtf + NF * 32;            // NF*32 fl
    float* wspf   = ktf + NF * 32;            // ~0.6M fl
    float* bbf    = wspf + 592000;            // 192 fl bias concat
    float* Sf     = wspf + 600000;            // E: NF*4096 fp8 bytes

    __bf16* h1t = (__bf16*)slabS1;            // (B,N,128)
    __bf16* h2t = (__bf16*)slabS2;            // (B,N,256)
    __bf16* h3t = (__bf16*)slabS1;            // (B,N,512)
    __bf16* h5t = (__bf16*)slabS2;            // (B,N,1024)
    float*  h4t = slabC;                      // (B,N,256) fp32
    uint8_t* vb1 = (uint8_t*)(slabC + NF * 256);  // (B,256,N) fp8
    float*  h6t = slabC;                      // (B,N,512) fp32
    uint8_t* vb2 = (uint8_t*)slabS1;          // (B,512,N) fp8
    __bf16* qkt = (__bf16*)qtf;               // (B,N,2CQ) packed [q|k]
    __bf16* wsp = (__bf16*)wspf;
    uint8_t* Sbuf = (uint8_t*)Sf;             // (B,4096,4096) fp8
    float*  sums = h1;                        // B*N floats

    __bf16* wsL2  = wsp;            // 128*128
    __bf16* wsL3  = wsL2 + 16384;   // 256*256
    __bf16* wsL4  = wsL3 + 65536;   // 512*512
    __bf16* wsA1q = wsL4 + 262144;  // 32*512   [combined with wsA1k]
    __bf16* wsA1k = wsA1q + 16384;
    __bf16* wsA1v = wsA1k + 16384;  // 256*512
    __bf16* wsA2q = wsA1v + 131072; // 64*1024  [combined with wsA2k]
    __bf16* wsA2k = wsA2q + 65536;
    __bf16* wsA2v = wsA2k + 65536;  // 512*1024

    dim3 blk(256);

    SigP sp;
    sp.W[0] = W1; sp.u[0] = u1; sp.O[0] = 64;  sp.C[0] = 6;
    sp.W[1] = W2; sp.u[1] = u2; sp.O[1] = 128; sp.C[1] = 64;
    sp.W[2] = W3; sp.u[2] = u3; sp.O[2] = 256; sp.C[2] = 128;
    sp.W[3] = W4; sp.u[3] = u4; sp.O[3] = 512; sp.C[3] = 256;
    sp.W[4] = W5; sp.u[4] = u5; sp.O[4] = 1;   sp.C[4] = 512;
    sigma_all<<<dim3(5), dim3(1024), 0, stream>>>(sp, sig);

    concat_bias<<<1, blk, 0, stream>>>(a1_qb, a1_kb, a2_qb, a2_kb, bbf);

    wsplit_kernel<<<128, blk, 0, stream>>>(W2, sig + 1, 1.f, 64, wsL2);
    wsplit_kernel<<<256, blk, 0, stream>>>(W3, sig + 2, 1.f, 128, wsL3);
    wsplit_kernel<<<512, blk, 0, stream>>>(W4, sig + 3, 1.f, 256, wsL4);
    wsplit_kernel<<<32,  blk, 0, stream>>>(a1_qW, nullptr, LOG2E, 256, wsA1q);
    wsplit_kernel<<<32,  blk, 0, stream>>>(a1_kW, nullptr, 1.f, 256, wsA1k);
    wsplit_kernel<<<256, blk, 0, stream>>>(a1_vW, nullptr, 1.f, 256, wsA1v);
    wsplit_kernel<<<64,  blk, 0, stream>>>(a2_qW, nullptr, LOG2E, 512, wsA2q);
    wsplit_kernel<<<64,  blk, 0, stream>>>(a2_kW, nullptr, 1.f, 512, wsA2k);
    wsplit_kernel<<<512, blk, 0, stream>>>(a2_vW, nullptr, 1.f, 512, wsA2v);

    // L1 (fp32) + transpose/split
    conv_f32_kernel<<<dim3(64, 1, 4), blk, 0, stream>>>(x, W1, b1, sig + 0, h1, 6, 64, 1);
    tsplit64_kernel<<<dim3(64, 4), blk, 0, stream>>>(h1, h1t);

    // L2, L3 (split-MFMA, MF=1)
    mfma_conv<4, 1, 1, 2, 0, 1><<<dim3(32, 2, 4), blk, 0, stream>>>(h1t, wsL2, b2, 1.f, h2t, 64, 128);
    mfma_conv<4, 1, 1, 2, 0, 1><<<dim3(32, 4, 4), blk, 0, stream>>>(h2t, wsL3, b3, 1.f, h3t, 128, 256);

    // attention 1 (C=256, Cq=32)
    mfma_conv<2, 2, 1, 4, 0, 0><<<dim3(16, 2, 4), blk, 0, stream>>>(h3t, wsA1q, bbf, 1.f, qkt, 256, 64);
    mfma_conv<4, 1, 1, 1, 0, 0><<<dim3(32, 4, 4), blk, 0, stream>>>(h3t, wsA1v, a1_vb, 1.f, vb1, 256, 256);
    hipMemsetAsync(sums, 0, NF * sizeof(float), stream);
    s_gemm<32><<<dim3(32, 32, 4), blk, 0, stream>>>(qkt, qkt + 32, Sbuf, sums, 64);
    pv_gemm7<2><<<dim3(1024), blk, 0, stream>>>(Sbuf, vb1, sums, h3t, a1_g, h4t, 256);

    // L4 (fp32-transposed input)
    mfma_conv<4, 1, 1, 2, 1, 1><<<dim3(32, 8, 4), blk, 0, stream>>>(h4t, wsL4, b4, 1.f, h5t, 256, 512);

    // attention 2 (C=512, Cq=64)
    mfma_conv<2, 2, 1, 4, 0, 0><<<dim3(16, 4, 4), blk, 0, stream>>>(h5t, wsA2q, bbf + 64, 1.f, qkt, 512, 128);
    mfma_conv<4, 1, 1, 1, 0, 0><<<dim3(32, 8, 4), blk, 0, stream>>>(h5t, wsA2v, a2_vb, 1.f, vb2, 512, 512);
    hipMemsetAsync(sums, 0, NF * sizeof(float), stream);
    s_gemm<64><<<dim3(32, 32, 4), blk, 0, stream>>>(qkt, qkt + 64, Sbuf, sums, 128);
    pv_gemm7<4><<<dim3(1024), blk, 0, stream>>>(Sbuf, vb2, sums, h5t, a2_g, h6t, 512);

    // L5
    l5_kernel<<<4096, blk, 0, stream>>>(h6t, W5, b5, sig + 4, (float*)d_out);
}